// Round 2
// baseline (57963.287 us; speedup 1.0000x reference)
//
#include <hip/hip_runtime.h>
#include <math.h>

#define B 64
#define P 196
#define ENCD 512
#define DECD 512
#define EMBD 256
#define ATTD 128
#define FFND 1024
#define VV 2000
#define MAXLEN 160
#define TSTEPS 159
#define EPS 1e-5f

// output chunk offsets (flat f32)
#define OUT_PRED ((size_t)0)
#define OUT_CAPS ((size_t)(B * TSTEPS * VV))
#define OUT_DECL (OUT_CAPS + (size_t)(B * MAXLEN))
#define OUT_ALPH (OUT_DECL + (size_t)B)
#define OUT_ORDR (OUT_ALPH + (size_t)(B * TSTEPS * P))

struct Ctx {
  // inputs
  const float* enc; const int* caps_in; const int* lens_in;
  const float* eaw; const float* eab; const float* daw; const float* dab;
  const float* faw; const float* fab;
  const float* gw1; const float* gb1; const float* gw2; const float* gb2;
  const float* emb;
  const float* wih1; const float* whh1; const float* bih1; const float* bhh1;
  const float* wih2; const float* whh2; const float* bih2; const float* bhh2;
  const float* projw; const float* projb;
  const float* ln1g; const float* ln1b; const float* ln2g; const float* ln2b;
  const float* fw1; const float* fb1; const float* fw2; const float* fb2;
  // ws
  int* bar;
  int* order_i; int* declen; int* caps_s;
  float* EaT; float* att1;
  float* h1; float* h2; float* v1; float* v2;
  float* gin; float* fg; float* gh1g; float* gh2g; float* p4;
  float* stats1; float* stats2;   // [2][64][2]
  float* WB1; float* WB2; float* WB3; float* WB4; float* WtA2;
  float* Sf; float* cbf; float* Sg; float* cbg;
  float* out;
};

__device__ __forceinline__ float sigf(float x) { return 1.f / (1.f + __expf(-x)); }

// ---------------- setup kernels ----------------

__global__ void k_order(Ctx c) {
  __shared__ int lens[B];
  int tid = threadIdx.x;
  lens[tid] = c.lens_in[tid];
  __syncthreads();
  int li = lens[tid];
  int pos = 0;
  for (int j = 0; j < B; ++j) {
    int lj = lens[j];
    pos += (lj > li || (lj == li && j < tid)) ? 1 : 0;
  }
  c.order_i[pos] = tid;
  c.declen[pos] = li - 1;
  c.out[OUT_ORDR + pos] = (float)tid;
  c.out[OUT_DECL + pos] = (float)(li - 1);
}

__global__ __launch_bounds__(256) void k_caps(Ctx c) {
  int idx = blockIdx.x * 256 + threadIdx.x;
  if (idx < B * MAXLEN) {
    int b = idx / MAXLEN, t = idx - b * MAXLEN;
    int v = c.caps_in[c.order_i[b] * MAXLEN + t];
    c.caps_s[idx] = v;
    c.out[OUT_CAPS + idx] = (float)v;
  }
}

// EaT[k*128 + d] = eaw[d*512 + k]
__global__ __launch_bounds__(256) void k_eat(Ctx c) {
  int idx = blockIdx.x * 256 + threadIdx.x;
  if (idx < 128 * 512) {
    int k = idx >> 7, d = idx & 127;
    c.EaT[(size_t)k * 128 + d] = c.eaw[(size_t)d * 512 + k];
  }
}

// att1[(b*P+p)*128 + d] = sum_k enc[ob,p,k]*eaw[d,k]  (no bias)
__global__ __launch_bounds__(256) void k_att1(Ctx c) {
  __shared__ float Xs[8 * 512];
  int tid = threadIdx.x;
  int r0 = blockIdx.x * 8;
  for (int idx = tid; idx < 8 * 512; idx += 256) {
    int rr = idx >> 9, k = idx & 511;
    int r = r0 + rr;
    int b = r / P, p = r - b * P;
    int ob = c.order_i[b];
    Xs[idx] = c.enc[((size_t)(ob * P + p)) * ENCD + k];
  }
  __syncthreads();
  int d = tid >> 1, kh = tid & 1;
  float acc[8];
#pragma unroll
  for (int rr = 0; rr < 8; ++rr) acc[rr] = 0.f;
  int kbase = kh * 256;
  for (int k = 0; k < 256; ++k) {
    float w = c.EaT[(size_t)(kbase + k) * 128 + d];
#pragma unroll
    for (int rr = 0; rr < 8; ++rr) acc[rr] = fmaf(w, Xs[rr * 512 + kbase + k], acc[rr]);
  }
#pragma unroll
  for (int rr = 0; rr < 8; ++rr) {
    acc[rr] += __shfl_xor(acc[rr], 1);
    if (kh == 0) c.att1[(size_t)(r0 + rr) * 128 + d] = acc[rr];
  }
}

// WB1: per g: [kk 0..31][slot 0..63][4]; slot c: j=c>>2, kz=c&3, k = kz*128+kk*4+i
__global__ __launch_bounds__(256) void k_wb1(Ctx c) {
  int g = blockIdx.x;
  float* dst = c.WB1 + (size_t)g * 8192;
  for (int idx = threadIdx.x; idx < 8192; idx += 256) {
    int i = idx & 3, cs = (idx >> 2) & 63, kk = idx >> 8;
    int j = cs >> 2, kz = cs & 3, k = kz * 128 + kk * 4 + i;
    float v;
    if (j < 6) v = c.whh1[(size_t)(6 * g + j) * 512 + k];
    else if (j < 12) v = c.whh2[(size_t)(6 * g + j - 6) * 512 + k];
    else v = c.ln2g[k] * c.fw1[(size_t)(4 * g + j - 12) * 512 + k];
    dst[idx] = v;
  }
}

// WB2: g=cg*4+z; slot c: j=c>>1 (col 32cg+j), kz2=c&1; k = z*256+kz2*128+kk*4+i
__global__ __launch_bounds__(256) void k_wb2(Ctx c) {
  int g = blockIdx.x;
  int cg = g >> 2, z = g & 3;
  float* dst = c.WB2 + (size_t)g * 8192;
  for (int idx = threadIdx.x; idx < 8192; idx += 256) {
    int i = idx & 3, cs = (idx >> 2) & 63, kk = idx >> 8;
    int j = cs >> 1, kz2 = cs & 1;
    int k = z * 256 + kz2 * 128 + kk * 4 + i;
    int v = cg * 32 + j;
    dst[idx] = (v < VV) ? c.fw2[(size_t)v * 1024 + k] : 0.f;
  }
}

// WB3: slot c: j=c>>3 (comp=j>>1, dd=j&1), kz=c&7; k = kz*96+kk*4+i; col = comp*512+2g+dd
__global__ __launch_bounds__(256) void k_wb3(Ctx c) {
  int g = blockIdx.x;
  float* dst = c.WB3 + (size_t)g * 6144;
  for (int idx = threadIdx.x; idx < 6144; idx += 256) {
    int i = idx & 3, cs = (idx >> 2) & 63, kk = idx >> 8;
    int j = cs >> 3, kz = cs & 7;
    int comp = j >> 1, dd = j & 1;
    int k = kz * 96 + kk * 4 + i;
    float v;
    if (comp < 3) v = c.wih1[(size_t)(comp * 512 + 2 * g + dd) * 768 + k];
    else v = c.projw[(size_t)(2 * g + dd) * 768 + k];
    dst[idx] = v;
  }
}

// WB4: slot c: j=c>>3 (<6; comp=j>>1, dd=j&1), kz=c&7; k = kz*64+kk*4+i; folded ln1g
__global__ __launch_bounds__(256) void k_wb4(Ctx c) {
  int g = blockIdx.x;
  float* dst = c.WB4 + (size_t)g * 4096;
  for (int idx = threadIdx.x; idx < 4096; idx += 256) {
    int i = idx & 3, cs = (idx >> 2) & 63, kk = idx >> 8;
    int j = cs >> 3, kz = cs & 7;
    float v = 0.f;
    if (j < 6) {
      int comp = j >> 1, dd = j & 1;
      int k = kz * 64 + kk * 4 + i;
      v = c.ln1g[k] * c.wih2[(size_t)(comp * 512 + 2 * g + dd) * 512 + k];
    }
    dst[idx] = v;
  }
}

__global__ __launch_bounds__(256) void k_wta2(Ctx c) {
  int idx = blockIdx.x * 256 + threadIdx.x;
  if (idx < 256 * 512) {
    int cc = idx >> 9, k = idx & 511;
    c.WtA2[idx] = (cc < 128) ? c.daw[(size_t)cc * 512 + k] : c.gw1[(size_t)(cc - 128) * 512 + k];
  }
}

// Sf/cbf (1024) and Sg/cbg (1536)
__global__ __launch_bounds__(256) void k_consts(Ctx c) {
  __shared__ float r1[256], r2[256];
  int i = blockIdx.x, tid = threadIdx.x;
  float a = 0.f, b2 = 0.f;
  if (i < 1024) {
    const float* w = c.fw1 + (size_t)i * 512;
    for (int k = tid; k < 512; k += 256) { a = fmaf(c.ln2g[k], w[k], a); b2 = fmaf(c.ln2b[k], w[k], b2); }
  } else {
    const float* w = c.wih2 + (size_t)(i - 1024) * 512;
    for (int k = tid; k < 512; k += 256) { a = fmaf(c.ln1g[k], w[k], a); b2 = fmaf(c.ln1b[k], w[k], b2); }
  }
  r1[tid] = a; r2[tid] = b2;
  __syncthreads();
  for (int s = 128; s > 0; s >>= 1) {
    if (tid < s) { r1[tid] += r1[tid + s]; r2[tid] += r2[tid + s]; }
    __syncthreads();
  }
  if (tid == 0) {
    if (i < 1024) { c.Sf[i] = r1[0]; c.cbf[i] = r2[0] + c.fb1[i]; }
    else { c.Sg[i - 1024] = r1[0]; c.cbg[i - 1024] = r2[0] + c.bih2[i - 1024]; }
  }
}

// ---------------- persistent kernel ----------------

__device__ __forceinline__ void gridbar(int* bar, int target) {
  __syncthreads();
  if (threadIdx.x == 0) {
    __threadfence();
    __hip_atomic_fetch_add(bar, 1, __ATOMIC_RELEASE, __HIP_MEMORY_SCOPE_AGENT);
    while (__hip_atomic_load(bar, __ATOMIC_ACQUIRE, __HIP_MEMORY_SCOPE_AGENT) < target) {
      __builtin_amdgcn_s_sleep(1);
    }
    __threadfence();
  }
  __syncthreads();
}

__global__ __launch_bounds__(512, 1) void persist(Ctx c) {
  __shared__ float sm[2048];
  const int g = blockIdx.x;
  const int tid = threadIdx.x;
  const int cslot = tid & 63;
  const int r = tid >> 6;  // 8 rowlanes, rows 8r..8r+7
  int phase = 0;

  for (int t = 0; t < MAXLEN; ++t) {
    // ================= S1: gh1 (6 cols), gh2 (6), f (4, LN2-folded) =================
    {
      if (tid < 64) {
        const float* s2 = c.stats2 + ((t + 1) & 1) * 128 + tid * 2;
        float m = s2[0] * (1.f / 512.f);
        float va = s2[1] * (1.f / 512.f) - m * m;
        sm[tid] = m;
        sm[64 + tid] = rsqrtf(va + EPS);
      }
      __syncthreads();
      const int j = cslot >> 2, kz = cslot & 3;
      const float* X;
      int colg;
      if (j < 6) { X = c.h1; colg = 6 * g + j; }
      else if (j < 12) { X = c.h2; colg = 6 * g + (j - 6); }
      else { X = c.v2; colg = 4 * g + (j - 12); }
      const float* wbase = c.WB1 + (size_t)g * 8192 + cslot * 4;
      const float* xbase = X + (size_t)(8 * r) * 512 + kz * 128;
      float acc[8] = {0.f, 0.f, 0.f, 0.f, 0.f, 0.f, 0.f, 0.f};
      for (int kk = 0; kk < 32; ++kk) {
        float4 w = *(const float4*)(wbase + kk * 256);
#pragma unroll
        for (int q = 0; q < 8; ++q) {
          float4 x = *(const float4*)(xbase + q * 512 + kk * 4);
          acc[q] = fmaf(w.x, x.x, fmaf(w.y, x.y, fmaf(w.z, x.z, fmaf(w.w, x.w, acc[q]))));
        }
      }
#pragma unroll
      for (int q = 0; q < 8; ++q) {
        acc[q] += __shfl_xor(acc[q], 1);
        acc[q] += __shfl_xor(acc[q], 2);
      }
      if (kz == 0) {
#pragma unroll
        for (int q = 0; q < 8; ++q) {
          int b = 8 * r + q;
          if (j < 6) c.gh1g[b * 1536 + colg] = acc[q];
          else if (j < 12) c.gh2g[b * 1536 + colg] = acc[q];
          else {
            float m2 = sm[b], i2 = sm[64 + b];
            c.fg[b * 1024 + colg] = i2 * (acc[q] - m2 * c.Sf[colg]) + c.cbf[colg];
          }
        }
      }
    }
    gridbar(c.bar, 256 * (++phase));

    // ================= S2: preds partial GEMM + attn/awe/gin + stats zero =================
    {
      const int j = cslot >> 1, kz2 = cslot & 1;
      const int cg = g >> 2, z = g & 3;
      const float* wbase = c.WB2 + (size_t)g * 8192 + cslot * 4;
      const float* xbase = c.fg + z * 256 + kz2 * 128 + (size_t)(8 * r) * 1024;
      float acc[8] = {0.f, 0.f, 0.f, 0.f, 0.f, 0.f, 0.f, 0.f};
      for (int kk = 0; kk < 32; ++kk) {
        float4 w = *(const float4*)(wbase + kk * 256);
#pragma unroll
        for (int q = 0; q < 8; ++q) {
          float4 x = *(const float4*)(xbase + q * 1024 + kk * 4);
          x.x = fmaxf(x.x, 0.f); x.y = fmaxf(x.y, 0.f); x.z = fmaxf(x.z, 0.f); x.w = fmaxf(x.w, 0.f);
          acc[q] = fmaf(w.x, x.x, fmaf(w.y, x.y, fmaf(w.z, x.z, fmaf(w.w, x.w, acc[q]))));
        }
      }
#pragma unroll
      for (int q = 0; q < 8; ++q) acc[q] += __shfl_xor(acc[q], 1);
      if (kz2 == 0) {
#pragma unroll
        for (int q = 0; q < 8; ++q) {
          int b = 8 * r + q;
          c.p4[(size_t)(z * 64 + b) * 2048 + 32 * cg + j] = acc[q];
        }
      }
      if (g == 0) {
        if (tid < 128) c.stats1[(t & 1) * 128 + tid] = 0.f;
        else if (tid < 256) c.stats2[(t & 1) * 128 + (tid - 128)] = 0.f;
      }
      if ((g & 3) == 3) {
        const int b = g >> 2;
        float* h2s = sm;            // 512
        float* a2g = sm + 512;      // 256
        float* red = sm + 768;      // 512
        float* att2s = sm + 1280;   // 128
        float* fawS = sm + 1408;    // 128
        float* alphas = sm + 1536;  // 224
        __syncthreads();
        h2s[tid] = c.h2[b * 512 + tid];
        __syncthreads();
        {
          int cc = tid >> 1, kh = tid & 1;
          const float* wp = c.WtA2 + (size_t)cc * 512 + kh * 256;
          const float* xp = h2s + kh * 256;
          float a = 0.f;
          for (int k = 0; k < 256; k += 4) {
            float4 w = *(const float4*)(wp + k);
            float4 x = *(const float4*)(xp + k);
            a = fmaf(w.x, x.x, fmaf(w.y, x.y, fmaf(w.z, x.z, fmaf(w.w, x.w, a))));
          }
          a += __shfl_xor(a, 1);
          if (kh == 0) a2g[cc] = a;
        }
        __syncthreads();
        if (tid < 128) {
          att2s[tid] = a2g[tid] + c.dab[tid] + c.eab[tid];
          fawS[tid] = c.faw[tid];
          float g1 = fmaxf(a2g[128 + tid] + c.gb1[tid], 0.f);
          red[tid] = g1 * c.gw2[tid];
        }
        __syncthreads();
        for (int s = 64; s > 0; s >>= 1) {
          if (tid < s) red[tid] += red[tid + s];
          __syncthreads();
        }
        float gatev = sigf(red[0] + c.gb2[0]);
        __syncthreads();
        float ev = -3.0e38f;
        if (tid < P) {
          const float* a1p = c.att1 + ((size_t)b * P + tid) * 128;
          float a = c.fab[0];
#pragma unroll 4
          for (int jj = 0; jj < 128; ++jj) a = fmaf(fmaxf(a1p[jj] + att2s[jj], 0.f), fawS[jj], a);
          ev = a;
        }
        red[tid] = ev;
        __syncthreads();
        for (int s = 256; s > 0; s >>= 1) {
          if (tid < s) red[tid] = fmaxf(red[tid], red[tid + s]);
          __syncthreads();
        }
        float mx = red[0];
        __syncthreads();
        float ex = (tid < P) ? __expf(ev - mx) : 0.f;
        red[tid] = ex;
        __syncthreads();
        for (int s = 256; s > 0; s >>= 1) {
          if (tid < s) red[tid] += red[tid + s];
          __syncthreads();
        }
        float inv = 1.f / red[0];
        if (tid < P) {
          float al = ex * inv;
          alphas[tid] = al;
          if (t < c.declen[b]) c.out[OUT_ALPH + ((size_t)b * TSTEPS + t) * P + tid] = al;
        }
        __syncthreads();
        {
          const int ob = c.order_i[b];
          const float* ep = c.enc + (size_t)ob * P * ENCD + tid;
          float a = 0.f;
#pragma unroll 4
          for (int p = 0; p < P; ++p) a = fmaf(alphas[p], ep[(size_t)p * ENCD], a);
          c.gin[b * 768 + 256 + tid] = a * gatev;
        }
        if (tid < 256) {
          int tok = c.caps_s[b * MAXLEN + t];
          c.gin[b * 768 + tid] = c.emb[(size_t)tok * 256 + tid];
        }
      }
    }
    gridbar(c.bar, 256 * (++phase));

    // ================= S3: giP GEMM + GRU1 gates + v1 + stats1 =================
    {
      const int j = cslot >> 3, kz = cslot & 7;
      const float* wbase = c.WB3 + (size_t)g * 6144 + cslot * 4;
      const float* xbase = c.gin + kz * 96 + (size_t)(8 * r) * 768;
      float acc[8] = {0.f, 0.f, 0.f, 0.f, 0.f, 0.f, 0.f, 0.f};
      for (int kk = 0; kk < 24; ++kk) {
        float4 w = *(const float4*)(wbase + kk * 256);
#pragma unroll
        for (int q = 0; q < 8; ++q) {
          float4 x = *(const float4*)(xbase + q * 768 + kk * 4);
          acc[q] = fmaf(w.x, x.x, fmaf(w.y, x.y, fmaf(w.z, x.z, fmaf(w.w, x.w, acc[q]))));
        }
      }
#pragma unroll
      for (int q = 0; q < 8; ++q) {
        acc[q] += __shfl_xor(acc[q], 1);
        acc[q] += __shfl_xor(acc[q], 2);
        acc[q] += __shfl_xor(acc[q], 4);
      }
      if (kz == 0) {
#pragma unroll
        for (int q = 0; q < 8; ++q) sm[j * 64 + 8 * r + q] = acc[q];
      }
      __syncthreads();
      if (tid < 128) {
        int b = tid >> 1, dd = tid & 1, d = 2 * g + dd;
        float ir = sm[(0 + dd) * 64 + b] + c.bih1[d];
        float iz = sm[(2 + dd) * 64 + b] + c.bih1[512 + d];
        float ig = sm[(4 + dd) * 64 + b] + c.bih1[1024 + d];
        float pj = sm[(6 + dd) * 64 + b] + c.projb[d];
        float hr = c.gh1g[b * 1536 + d] + c.bhh1[d];
        float hz = c.gh1g[b * 1536 + 512 + d] + c.bhh1[512 + d];
        float hg = c.gh1g[b * 1536 + 1024 + d] + c.bhh1[1024 + d];
        float rr_ = sigf(ir + hr);
        float zz = sigf(iz + hz);
        float nn = tanhf(ig + rr_ * hg);
        float hold = c.h1[b * 512 + d];
        float hnew = (1.f - zz) * nn + zz * hold;
        c.h1[b * 512 + d] = (t < c.declen[b]) ? hnew : hold;
        float v1v = hnew + pj;
        c.v1[b * 512 + d] = v1v;
        float q2 = v1v * v1v;
        float s = v1v + __shfl_xor(v1v, 1);
        float sq = q2 + __shfl_xor(q2, 1);
        if (dd == 0) {
          atomicAdd(&c.stats1[(t & 1) * 128 + b * 2 + 0], s);
          atomicAdd(&c.stats1[(t & 1) * 128 + b * 2 + 1], sq);
        }
      }
    }
    gridbar(c.bar, 256 * (++phase));

    // ================= S4: gi2 GEMM (LN1-folded) + GRU2 + v2 + stats2 + preds store =================
    {
      if (t > 0) {
        int b = g >> 2, seg = g & 3;
        int tp = t - 1;
        if (tp < c.declen[b] && tid < 500) {
          int v = seg * 500 + tid;
          if (v < VV) {
            float s = c.fb2[v];
#pragma unroll
            for (int z = 0; z < 4; ++z) s += c.p4[(size_t)(z * 64 + b) * 2048 + v];
            c.out[OUT_PRED + ((size_t)b * TSTEPS + tp) * VV + v] = s;
          }
        }
      }
      const int j = cslot >> 3, kz = cslot & 7;
      float acc[8] = {0.f, 0.f, 0.f, 0.f, 0.f, 0.f, 0.f, 0.f};
      if (j < 6) {
        const float* wbase = c.WB4 + (size_t)g * 4096 + cslot * 4;
        const float* xbase = c.v1 + kz * 64 + (size_t)(8 * r) * 512;
        for (int kk = 0; kk < 16; ++kk) {
          float4 w = *(const float4*)(wbase + kk * 256);
#pragma unroll
          for (int q = 0; q < 8; ++q) {
            float4 x = *(const float4*)(xbase + q * 512 + kk * 4);
            acc[q] = fmaf(w.x, x.x, fmaf(w.y, x.y, fmaf(w.z, x.z, fmaf(w.w, x.w, acc[q]))));
          }
        }
      }
#pragma unroll
      for (int q = 0; q < 8; ++q) {
        acc[q] += __shfl_xor(acc[q], 1);
        acc[q] += __shfl_xor(acc[q], 2);
        acc[q] += __shfl_xor(acc[q], 4);
      }
      __syncthreads();
      if (kz == 0 && j < 6) {
#pragma unroll
        for (int q = 0; q < 8; ++q) sm[j * 64 + 8 * r + q] = acc[q];
      }
      __syncthreads();
      if (tid < 128) {
        int b = tid >> 1, dd = tid & 1, d = 2 * g + dd;
        const float* s1 = c.stats1 + (t & 1) * 128 + b * 2;
        float m1 = s1[0] * (1.f / 512.f);
        float va = s1[1] * (1.f / 512.f) - m1 * m1;
        float i1 = rsqrtf(va + EPS);
        int c0 = d, c1 = 512 + d, c2 = 1024 + d;
        float gir = i1 * (sm[(0 + dd) * 64 + b] - m1 * c.Sg[c0]) + c.cbg[c0];
        float giz = i1 * (sm[(2 + dd) * 64 + b] - m1 * c.Sg[c1]) + c.cbg[c1];
        float gig = i1 * (sm[(4 + dd) * 64 + b] - m1 * c.Sg[c2]) + c.cbg[c2];
        float hr = c.gh2g[b * 1536 + d] + c.bhh2[d];
        float hz = c.gh2g[b * 1536 + 512 + d] + c.bhh2[512 + d];
        float hg = c.gh2g[b * 1536 + 1024 + d] + c.bhh2[1024 + d];
        float r2 = sigf(gir + hr);
        float z2 = sigf(giz + hz);
        float n2 = tanhf(gig + r2 * hg);
        float hold = c.h2[b * 512 + d];
        float hnew = (1.f - z2) * n2 + z2 * hold;
        c.h2[b * 512 + d] = (t < c.declen[b]) ? hnew : hold;
        float h1r = (c.v1[b * 512 + d] - m1) * i1 * c.ln1g[d] + c.ln1b[d];
        float v2v = hnew + h1r;
        c.v2[b * 512 + d] = v2v;
        float q2 = v2v * v2v;
        float s = v2v + __shfl_xor(v2v, 1);
        float sq = q2 + __shfl_xor(q2, 1);
        if (dd == 0) {
          atomicAdd(&c.stats2[(t & 1) * 128 + b * 2 + 0], s);
          atomicAdd(&c.stats2[(t & 1) * 128 + b * 2 + 1], sq);
        }
      }
    }
    gridbar(c.bar, 256 * (++phase));
  }
}

extern "C" void kernel_launch(void* const* d_in, const int* in_sizes, int n_in,
                              void* d_out, int out_size, void* d_ws, size_t ws_size,
                              hipStream_t stream) {
  (void)in_sizes; (void)n_in; (void)ws_size;
  Ctx c;
  c.enc = (const float*)d_in[0];
  c.caps_in = (const int*)d_in[1];
  c.lens_in = (const int*)d_in[2];
  c.eaw = (const float*)d_in[3];
  c.eab = (const float*)d_in[4];
  c.daw = (const float*)d_in[5];
  c.dab = (const float*)d_in[6];
  c.faw = (const float*)d_in[7];
  c.fab = (const float*)d_in[8];
  c.gw1 = (const float*)d_in[9];
  c.gb1 = (const float*)d_in[10];
  c.gw2 = (const float*)d_in[11];
  c.gb2 = (const float*)d_in[12];
  c.emb = (const float*)d_in[13];
  c.wih1 = (const float*)d_in[14];
  c.whh1 = (const float*)d_in[15];
  c.bih1 = (const float*)d_in[16];
  c.bhh1 = (const float*)d_in[17];
  c.wih2 = (const float*)d_in[18];
  c.whh2 = (const float*)d_in[19];
  c.bih2 = (const float*)d_in[20];
  c.bhh2 = (const float*)d_in[21];
  c.projw = (const float*)d_in[22];
  c.projb = (const float*)d_in[23];
  c.ln1g = (const float*)d_in[24];
  c.ln1b = (const float*)d_in[25];
  c.ln2g = (const float*)d_in[26];
  c.ln2b = (const float*)d_in[27];
  c.fw1 = (const float*)d_in[28];
  c.fb1 = (const float*)d_in[29];
  c.fw2 = (const float*)d_in[30];
  c.fb2 = (const float*)d_in[31];
  c.out = (float*)d_out;

  char* wp_ = (char*)d_ws;
  auto alloc = [&](size_t bytes) -> char* {
    char* p = wp_;
    wp_ += (bytes + 255) & ~(size_t)255;
    return p;
  };
  // zero-region (one memset): bar | h1 | h2 | stats1 | stats2
  char* zbase = wp_;
  c.bar = (int*)alloc(256);
  c.h1 = (float*)alloc((size_t)B * 512 * 4);
  c.h2 = (float*)alloc((size_t)B * 512 * 4);
  c.stats1 = (float*)alloc(2 * 64 * 2 * 4);
  c.stats2 = (float*)alloc(2 * 64 * 2 * 4);
  size_t zbytes = (size_t)(wp_ - zbase);

  c.order_i = (int*)alloc(B * 4);
  c.declen = (int*)alloc(B * 4);
  c.caps_s = (int*)alloc((size_t)B * MAXLEN * 4);
  c.EaT = (float*)alloc((size_t)512 * 128 * 4);
  c.att1 = (float*)alloc((size_t)B * P * 128 * 4);
  c.v1 = (float*)alloc((size_t)B * 512 * 4);
  c.v2 = (float*)alloc((size_t)B * 512 * 4);
  c.gin = (float*)alloc((size_t)B * 768 * 4);
  c.fg = (float*)alloc((size_t)B * 1024 * 4);
  c.gh1g = (float*)alloc((size_t)B * 1536 * 4);
  c.gh2g = (float*)alloc((size_t)B * 1536 * 4);
  c.p4 = (float*)alloc((size_t)4 * B * 2048 * 4);
  c.WB1 = (float*)alloc((size_t)256 * 8192 * 4);
  c.WB2 = (float*)alloc((size_t)256 * 8192 * 4);
  c.WB3 = (float*)alloc((size_t)256 * 6144 * 4);
  c.WB4 = (float*)alloc((size_t)256 * 4096 * 4);
  c.WtA2 = (float*)alloc((size_t)256 * 512 * 4);
  c.Sf = (float*)alloc(1024 * 4);
  c.cbf = (float*)alloc(1024 * 4);
  c.Sg = (float*)alloc(1536 * 4);
  c.cbg = (float*)alloc(1536 * 4);

  hipMemsetAsync(d_out, 0, (size_t)out_size * 4, stream);
  hipMemsetAsync(zbase, 0, zbytes, stream);

  k_order<<<1, 64, 0, stream>>>(c);
  k_caps<<<(B * MAXLEN + 255) / 256, 256, 0, stream>>>(c);
  k_eat<<<(128 * 512 + 255) / 256, 256, 0, stream>>>(c);
  k_att1<<<(B * P) / 8, 256, 0, stream>>>(c);
  k_wb1<<<256, 256, 0, stream>>>(c);
  k_wb2<<<256, 256, 0, stream>>>(c);
  k_wb3<<<256, 256, 0, stream>>>(c);
  k_wb4<<<256, 256, 0, stream>>>(c);
  k_wta2<<<512, 256, 0, stream>>>(c);
  k_consts<<<2560, 256, 0, stream>>>(c);

  persist<<<256, 512, 0, stream>>>(c);
}

// Round 3
// 56244.836 us; speedup vs baseline: 1.0306x; 1.0306x over previous
//
#include <hip/hip_runtime.h>
#include <math.h>

#define B 64
#define P 196
#define ENCD 512
#define DECD 512
#define EMBD 256
#define ATTD 128
#define FFND 1024
#define VV 2000
#define MAXLEN 160
#define TSTEPS 159
#define EPS 1e-5f

// output chunk offsets (flat f32)
#define OUT_PRED ((size_t)0)
#define OUT_CAPS ((size_t)(B * TSTEPS * VV))
#define OUT_DECL (OUT_CAPS + (size_t)(B * MAXLEN))
#define OUT_ALPH (OUT_DECL + (size_t)B)
#define OUT_ORDR (OUT_ALPH + (size_t)(B * TSTEPS * P))

struct Ctx {
  // inputs
  const float* enc; const int* caps_in; const int* lens_in;
  const float* eaw; const float* eab; const float* daw; const float* dab;
  const float* faw; const float* fab;
  const float* gw1; const float* gb1; const float* gw2; const float* gb2;
  const float* emb;
  const float* wih1; const float* whh1; const float* bih1; const float* bhh1;
  const float* wih2; const float* whh2; const float* bih2; const float* bhh2;
  const float* projw; const float* projb;
  const float* ln1g; const float* ln1b; const float* ln2g; const float* ln2b;
  const float* fw1; const float* fb1; const float* fw2; const float* fb2;
  // ws
  int* leafs; int* root;
  int* order_i; int* declen; int* caps_s;
  float* EaT; float* att1;
  float* h1; float* h2; float* v1; float* v2;
  float* gin; float* fg; float* gh1g; float* gh2g;
  float* att2acc; float* eP;
  float* stats1; float* stats2;   // [2][64][2]
  float* WB1; float* WB2; float* WB3; float* WB4; float* WtA2;
  float* Sf; float* cbf; float* Sg; float* cbg;
  float* out;
};

__device__ __forceinline__ float sigf(float x) { return 1.f / (1.f + __expf(-x)); }

// ---------------- setup kernels ----------------

__global__ void k_order(Ctx c) {
  __shared__ int lens[B];
  int tid = threadIdx.x;
  lens[tid] = c.lens_in[tid];
  __syncthreads();
  int li = lens[tid];
  int pos = 0;
  for (int j = 0; j < B; ++j) {
    int lj = lens[j];
    pos += (lj > li || (lj == li && j < tid)) ? 1 : 0;
  }
  c.order_i[pos] = tid;
  c.declen[pos] = li - 1;
  c.out[OUT_ORDR + pos] = (float)tid;
  c.out[OUT_DECL + pos] = (float)(li - 1);
}

__global__ __launch_bounds__(256) void k_caps(Ctx c) {
  int idx = blockIdx.x * 256 + threadIdx.x;
  if (idx < B * MAXLEN) {
    int b = idx / MAXLEN, t = idx - b * MAXLEN;
    int v = c.caps_in[c.order_i[b] * MAXLEN + t];
    c.caps_s[idx] = v;
    c.out[OUT_CAPS + idx] = (float)v;
  }
}

__global__ __launch_bounds__(256) void k_eat(Ctx c) {
  int idx = blockIdx.x * 256 + threadIdx.x;
  if (idx < 128 * 512) {
    int k = idx >> 7, d = idx & 127;
    c.EaT[(size_t)k * 128 + d] = c.eaw[(size_t)d * 512 + k];
  }
}

// att1[(b*P+p)*128 + d] = sum_k enc[ob,p,k]*eaw[d,k]  (no bias)
__global__ __launch_bounds__(256) void k_att1(Ctx c) {
  __shared__ float Xs[8 * 512];
  int tid = threadIdx.x;
  int r0 = blockIdx.x * 8;
  for (int idx = tid; idx < 8 * 512; idx += 256) {
    int rr = idx >> 9, k = idx & 511;
    int r = r0 + rr;
    int b = r / P, p = r - b * P;
    int ob = c.order_i[b];
    Xs[idx] = c.enc[((size_t)(ob * P + p)) * ENCD + k];
  }
  __syncthreads();
  int d = tid >> 1, kh = tid & 1;
  float acc[8];
#pragma unroll
  for (int rr = 0; rr < 8; ++rr) acc[rr] = 0.f;
  int kbase = kh * 256;
  for (int k = 0; k < 256; ++k) {
    float w = c.EaT[(size_t)(kbase + k) * 128 + d];
#pragma unroll
    for (int rr = 0; rr < 8; ++rr) acc[rr] = fmaf(w, Xs[rr * 512 + kbase + k], acc[rr]);
  }
#pragma unroll
  for (int rr = 0; rr < 8; ++rr) {
    acc[rr] += __shfl_xor(acc[rr], 1);
    if (kh == 0) c.att1[(size_t)(r0 + rr) * 128 + d] = acc[rr];
  }
}

// WB1: per g: [kk 0..31][slot 0..63][4]; slot c: j=c>>2, kz=c&3, k = kz*128+kk*4+i
__global__ __launch_bounds__(256) void k_wb1(Ctx c) {
  int g = blockIdx.x;
  float* dst = c.WB1 + (size_t)g * 8192;
  for (int idx = threadIdx.x; idx < 8192; idx += 256) {
    int i = idx & 3, cs = (idx >> 2) & 63, kk = idx >> 8;
    int j = cs >> 2, kz = cs & 3, k = kz * 128 + kk * 4 + i;
    float v;
    if (j < 6) v = c.whh1[(size_t)(6 * g + j) * 512 + k];
    else if (j < 12) v = c.whh2[(size_t)(6 * g + j - 6) * 512 + k];
    else v = c.ln2g[k] * c.fw1[(size_t)(4 * g + j - 12) * 512 + k];
    dst[idx] = v;
  }
}

// WB2 (full-K preds): per g: [kk 0..31][slot 0..63][4]; slot c: j=c>>3 (col 8g+j), kz=c&7, k=kz*128+kk*4+i
__global__ __launch_bounds__(256) void k_wb2(Ctx c) {
  int g = blockIdx.x;
  float* dst = c.WB2 + (size_t)g * 8192;
  for (int idx = threadIdx.x; idx < 8192; idx += 256) {
    int i = idx & 3, cs = (idx >> 2) & 63, kk = idx >> 8;
    int j = cs >> 3, kz = cs & 7;
    int k = kz * 128 + kk * 4 + i;
    int col = 8 * g + j;
    dst[idx] = (col < VV) ? c.fw2[(size_t)col * 1024 + k] : 0.f;
  }
}

// WB3: slot c: j=c>>3 (comp=j>>1, dd=j&1), kz=c&7; k = kz*96+kk*4+i; col = comp*512+2g+dd
__global__ __launch_bounds__(256) void k_wb3(Ctx c) {
  int g = blockIdx.x;
  float* dst = c.WB3 + (size_t)g * 6144;
  for (int idx = threadIdx.x; idx < 6144; idx += 256) {
    int i = idx & 3, cs = (idx >> 2) & 63, kk = idx >> 8;
    int j = cs >> 3, kz = cs & 7;
    int comp = j >> 1, dd = j & 1;
    int k = kz * 96 + kk * 4 + i;
    float v;
    if (comp < 3) v = c.wih1[(size_t)(comp * 512 + 2 * g + dd) * 768 + k];
    else v = c.projw[(size_t)(2 * g + dd) * 768 + k];
    dst[idx] = v;
  }
}

// WB4: slot c: j=c>>3 (<6; comp=j>>1, dd=j&1), kz=c&7; k = kz*64+kk*4+i; folded ln1g
__global__ __launch_bounds__(256) void k_wb4(Ctx c) {
  int g = blockIdx.x;
  float* dst = c.WB4 + (size_t)g * 4096;
  for (int idx = threadIdx.x; idx < 4096; idx += 256) {
    int i = idx & 3, cs = (idx >> 2) & 63, kk = idx >> 8;
    int j = cs >> 3, kz = cs & 7;
    float v = 0.f;
    if (j < 6) {
      int comp = j >> 1, dd = j & 1;
      int k = kz * 64 + kk * 4 + i;
      v = c.ln1g[k] * c.wih2[(size_t)(comp * 512 + 2 * g + dd) * 512 + k];
    }
    dst[idx] = v;
  }
}

__global__ __launch_bounds__(256) void k_wta2(Ctx c) {
  int idx = blockIdx.x * 256 + threadIdx.x;
  if (idx < 256 * 512) {
    int cc = idx >> 9, k = idx & 511;
    c.WtA2[idx] = (cc < 128) ? c.daw[(size_t)cc * 512 + k] : c.gw1[(size_t)(cc - 128) * 512 + k];
  }
}

// Sf/cbf (1024) and Sg/cbg (1536)
__global__ __launch_bounds__(256) void k_consts(Ctx c) {
  __shared__ float r1[256], r2[256];
  int i = blockIdx.x, tid = threadIdx.x;
  float a = 0.f, b2 = 0.f;
  if (i < 1024) {
    const float* w = c.fw1 + (size_t)i * 512;
    for (int k = tid; k < 512; k += 256) { a = fmaf(c.ln2g[k], w[k], a); b2 = fmaf(c.ln2b[k], w[k], b2); }
  } else {
    const float* w = c.wih2 + (size_t)(i - 1024) * 512;
    for (int k = tid; k < 512; k += 256) { a = fmaf(c.ln1g[k], w[k], a); b2 = fmaf(c.ln1b[k], w[k], b2); }
  }
  r1[tid] = a; r2[tid] = b2;
  __syncthreads();
  for (int s = 128; s > 0; s >>= 1) {
    if (tid < s) { r1[tid] += r1[tid + s]; r2[tid] += r2[tid + s]; }
    __syncthreads();
  }
  if (tid == 0) {
    if (i < 1024) { c.Sf[i] = r1[0]; c.cbf[i] = r2[0] + c.fb1[i]; }
    else { c.Sg[i - 1024] = r1[0]; c.cbg[i - 1024] = r2[0] + c.bih2[i - 1024]; }
  }
}

// ---------------- persistent kernel ----------------

__device__ __forceinline__ void gridbar(int* leafs, int* root, int ph) {
  __syncthreads();
  if (threadIdx.x == 0) {
    __threadfence();
    int old = __hip_atomic_fetch_add(&leafs[(blockIdx.x >> 5) * 32], 1,
                                     __ATOMIC_ACQ_REL, __HIP_MEMORY_SCOPE_AGENT);
    if (old == ph * 32 - 1)
      __hip_atomic_fetch_add(root, 1, __ATOMIC_ACQ_REL, __HIP_MEMORY_SCOPE_AGENT);
    while (__hip_atomic_load(root, __ATOMIC_ACQUIRE, __HIP_MEMORY_SCOPE_AGENT) < ph * 8)
      __builtin_amdgcn_s_sleep(2);
    __threadfence();
  }
  __syncthreads();
}

__global__ __launch_bounds__(512, 2) void persist(Ctx c) {
  __shared__ float att1s[6272];
  __shared__ float sm[2048];
  __shared__ float alphaS[256];
  __shared__ float constS[512];
  __shared__ int declenI[64];
  __shared__ float gateS_sh;
  const int g = blockIdx.x;
  const int tid = threadIdx.x;
  const int cslot = tid & 63;
  const int r = tid >> 6;        // 8 rowlane groups: rows 8r..8r+7
  const int b = g >> 2, q = g & 3;
  const int el = tid & 127, pb = tid >> 7;  // enc-register layout

  // ---- one-time staging ----
  for (int i = tid; i < 6272; i += 512) att1s[i] = c.att1[((size_t)b * P + 49 * q) * 128 + i];
  if (tid < 128) {
    constS[tid] = c.faw[tid];
    constS[128 + tid] = c.dab[tid] + c.eab[tid];
    constS[256 + tid] = c.gb1[tid];
  }
  if (tid == 0) { constS[384] = c.gb2[0]; constS[385] = c.fab[0]; }
  if (tid < 64) declenI[tid] = c.declen[tid];
  float encR[49];  // enc[b, pb*49+i, q*128+el]
  {
    const int ob = c.order_i[b];
    const float* ep = c.enc + ((size_t)(ob * P) + (size_t)pb * 49) * ENCD + q * 128 + el;
#pragma unroll
    for (int i = 0; i < 49; ++i) encR[i] = ep[(size_t)i * ENCD];
  }
  __syncthreads();

  int ph = 0;
  for (int t = 0; t < MAXLEN; ++t) {
    // ========== Phase1: gh1(6), gh2(6), fg(4, LN2-folded) GEMMs + att2/gate1 column ==========
    {
      if (tid < 64) {
        const float* s2 = c.stats2 + ((t + 1) & 1) * 128 + tid * 2;
        float m = s2[0] * (1.f / 512.f);
        float va = s2[1] * (1.f / 512.f) - m * m;
        sm[tid] = m;
        sm[64 + tid] = rsqrtf(va + EPS);
      }
      __syncthreads();
      const int j = cslot >> 2, kz = cslot & 3;
      const float* X;
      int colg;
      if (j < 6) { X = c.h1; colg = 6 * g + j; }
      else if (j < 12) { X = c.h2; colg = 6 * g + (j - 6); }
      else { X = c.v2; colg = 4 * g + (j - 12); }
      const float* wbase = c.WB1 + (size_t)g * 8192 + cslot * 4;
      const float* xbase = X + (size_t)(8 * r) * 512 + kz * 128;
      float acc[8] = {0.f, 0.f, 0.f, 0.f, 0.f, 0.f, 0.f, 0.f};
      for (int kk = 0; kk < 32; ++kk) {
        float4 w = *(const float4*)(wbase + kk * 256);
#pragma unroll
        for (int qq = 0; qq < 8; ++qq) {
          float4 x = *(const float4*)(xbase + qq * 512 + kk * 4);
          acc[qq] = fmaf(w.x, x.x, fmaf(w.y, x.y, fmaf(w.z, x.z, fmaf(w.w, x.w, acc[qq]))));
        }
      }
#pragma unroll
      for (int qq = 0; qq < 8; ++qq) {
        acc[qq] += __shfl_xor(acc[qq], 1);
        acc[qq] += __shfl_xor(acc[qq], 2);
      }
      if (kz == 0) {
#pragma unroll
        for (int qq = 0; qq < 8; ++qq) {
          int bb = 8 * r + qq;
          if (j < 6) c.gh1g[bb * 1536 + colg] = acc[qq];
          else if (j < 12) c.gh2g[bb * 1536 + colg] = acc[qq];
          else {
            float m2 = sm[bb], i2 = sm[64 + bb];
            c.fg[bb * 1024 + colg] = i2 * (acc[qq] - m2 * c.Sf[colg]) + c.cbf[colg];
          }
        }
      }
      // att2/gate1 column g: att2acc[b8, g] = h2[b8,:] . WtA2[g,:]
      {
        const int b8 = tid >> 3, kl = tid & 7;
        const float* hp = c.h2 + b8 * 512 + kl * 64;
        const float* wp = c.WtA2 + (size_t)g * 512 + kl * 64;
        float a = 0.f;
        for (int k = 0; k < 64; k += 4) {
          float4 xx = *(const float4*)(hp + k);
          float4 ww = *(const float4*)(wp + k);
          a = fmaf(ww.x, xx.x, fmaf(ww.y, xx.y, fmaf(ww.z, xx.z, fmaf(ww.w, xx.w, a))));
        }
        a += __shfl_xor(a, 1); a += __shfl_xor(a, 2); a += __shfl_xor(a, 4);
        if (kl == 0) c.att2acc[b8 * 256 + g] = a;
      }
    }
    gridbar(c.leafs, c.root, ++ph);

    // ========== Phase2: preds full-K GEMM (store t-1) + gate + e-partials + stats zero ==========
    {
      if (g == 0) {
        if (tid < 128) c.stats1[(t & 1) * 128 + tid] = 0.f;
        else if (tid < 256) c.stats2[(t & 1) * 128 + (tid - 128)] = 0.f;
      }
      const int j = cslot >> 3, kz = cslot & 7;
      const int col = 8 * g + j;
      const float* wbase = c.WB2 + (size_t)g * 8192 + cslot * 4;
      const float* xbase = c.fg + kz * 128 + (size_t)(8 * r) * 1024;
      float acc[8] = {0.f, 0.f, 0.f, 0.f, 0.f, 0.f, 0.f, 0.f};
      for (int kk = 0; kk < 32; ++kk) {
        float4 w = *(const float4*)(wbase + kk * 256);
#pragma unroll
        for (int qq = 0; qq < 8; ++qq) {
          float4 x = *(const float4*)(xbase + qq * 1024 + kk * 4);
          x.x = fmaxf(x.x, 0.f); x.y = fmaxf(x.y, 0.f); x.z = fmaxf(x.z, 0.f); x.w = fmaxf(x.w, 0.f);
          acc[qq] = fmaf(w.x, x.x, fmaf(w.y, x.y, fmaf(w.z, x.z, fmaf(w.w, x.w, acc[qq]))));
        }
      }
#pragma unroll
      for (int qq = 0; qq < 8; ++qq) {
        acc[qq] += __shfl_xor(acc[qq], 1);
        acc[qq] += __shfl_xor(acc[qq], 2);
        acc[qq] += __shfl_xor(acc[qq], 4);
      }
      if (kz == 0 && col < VV && t > 0) {
        int tp = t - 1;
        float bias = c.fb2[col];
#pragma unroll
        for (int qq = 0; qq < 8; ++qq) {
          int br = 8 * r + qq;
          if (tp < declenI[br])
            c.out[OUT_PRED + ((size_t)br * TSTEPS + tp) * VV + col] = acc[qq] + bias;
        }
      }
      // gate + e-partials for this block's 49 p's
      __syncthreads();
      if (tid < 128) {
        sm[tid] = c.att2acc[b * 256 + tid] + constS[128 + tid];  // att2s
        float g1 = fmaxf(c.att2acc[b * 256 + 128 + tid] + constS[256 + tid], 0.f);
        sm[256 + tid] = g1 * c.gw2[tid];
      }
      __syncthreads();
      for (int s = 64; s > 0; s >>= 1) {
        if (tid < s) sm[256 + tid] += sm[256 + tid + s];
        __syncthreads();
      }
      if (tid == 0) gateS_sh = sigf(sm[256] + constS[384]);
      const int pg = tid >> 3, jl = tid & 7;
      float epart = 0.f;
      if (pg < 49) {
#pragma unroll
        for (int jj = 0; jj < 16; ++jj) {
          int jI = jl * 16 + jj;
          epart = fmaf(fmaxf(att1s[pg * 128 + jI] + sm[jI], 0.f), constS[jI], epart);
        }
      }
      epart += __shfl_xor(epart, 1); epart += __shfl_xor(epart, 2); epart += __shfl_xor(epart, 4);
      if (jl == 0 && pg < 49) c.eP[b * 256 + 49 * q + pg] = epart + constS[385];
    }
    gridbar(c.leafs, c.root, ++ph);

    // ========== Phase3: softmax + alpha out + awe (register enc) + gin assembly ==========
    {
      float ev = (tid < P) ? c.eP[b * 256 + tid] : -3.0e38f;
      sm[tid] = ev;
      __syncthreads();
      for (int s = 256; s > 0; s >>= 1) {
        if (tid < s) sm[tid] = fmaxf(sm[tid], sm[tid + s]);
        __syncthreads();
      }
      float mx = sm[0];
      __syncthreads();
      float ex = (tid < P) ? __expf(ev - mx) : 0.f;
      sm[tid] = ex;
      __syncthreads();
      for (int s = 256; s > 0; s >>= 1) {
        if (tid < s) sm[tid] += sm[tid + s];
        __syncthreads();
      }
      float inv = 1.f / sm[0];
      float al = ex * inv;
      if (tid < 256) alphaS[tid] = al;
      __syncthreads();
      if (tid >= 49 * q && tid < 49 * (q + 1) && t < declenI[b])
        c.out[OUT_ALPH + ((size_t)b * TSTEPS + t) * P + tid] = al;
      float s_ = 0.f;
#pragma unroll
      for (int i = 0; i < 49; ++i) s_ = fmaf(alphaS[pb * 49 + i], encR[i], s_);
      sm[1024 + tid] = s_;
      __syncthreads();
      if (tid < 128) {
        float tot = sm[1024 + tid] + sm[1152 + tid] + sm[1280 + tid] + sm[1408 + tid];
        c.gin[b * 768 + 256 + q * 128 + tid] = tot * gateS_sh;
      }
      if (q == 1 && tid < 256) {
        int tok = c.caps_s[b * MAXLEN + t];
        c.gin[b * 768 + tid] = c.emb[(size_t)tok * 256 + tid];
      }
    }
    gridbar(c.leafs, c.root, ++ph);

    // ========== Phase4: giP GEMM + GRU1 + v1 + stats1 ==========
    {
      const int j = cslot >> 3, kz = cslot & 7;
      const float* wbase = c.WB3 + (size_t)g * 6144 + cslot * 4;
      const float* xbase = c.gin + kz * 96 + (size_t)(8 * r) * 768;
      float acc[8] = {0.f, 0.f, 0.f, 0.f, 0.f, 0.f, 0.f, 0.f};
      for (int kk = 0; kk < 24; ++kk) {
        float4 w = *(const float4*)(wbase + kk * 256);
#pragma unroll
        for (int qq = 0; qq < 8; ++qq) {
          float4 x = *(const float4*)(xbase + qq * 768 + kk * 4);
          acc[qq] = fmaf(w.x, x.x, fmaf(w.y, x.y, fmaf(w.z, x.z, fmaf(w.w, x.w, acc[qq]))));
        }
      }
#pragma unroll
      for (int qq = 0; qq < 8; ++qq) {
        acc[qq] += __shfl_xor(acc[qq], 1);
        acc[qq] += __shfl_xor(acc[qq], 2);
        acc[qq] += __shfl_xor(acc[qq], 4);
      }
      if (kz == 0) {
#pragma unroll
        for (int qq = 0; qq < 8; ++qq) sm[j * 64 + 8 * r + qq] = acc[qq];
      }
      __syncthreads();
      if (tid < 128) {
        int bb = tid >> 1, dd = tid & 1, d = 2 * g + dd;
        float ir = sm[(0 + dd) * 64 + bb] + c.bih1[d];
        float iz = sm[(2 + dd) * 64 + bb] + c.bih1[512 + d];
        float ig = sm[(4 + dd) * 64 + bb] + c.bih1[1024 + d];
        float pj = sm[(6 + dd) * 64 + bb] + c.projb[d];
        float hr = c.gh1g[bb * 1536 + d] + c.bhh1[d];
        float hz = c.gh1g[bb * 1536 + 512 + d] + c.bhh1[512 + d];
        float hg = c.gh1g[bb * 1536 + 1024 + d] + c.bhh1[1024 + d];
        float rr_ = sigf(ir + hr);
        float zz = sigf(iz + hz);
        float nn = tanhf(ig + rr_ * hg);
        float hold = c.h1[bb * 512 + d];
        float hnew = (1.f - zz) * nn + zz * hold;
        c.h1[bb * 512 + d] = (t < declenI[bb]) ? hnew : hold;
        float v1v = hnew + pj;
        c.v1[bb * 512 + d] = v1v;
        float q2 = v1v * v1v;
        float s = v1v + __shfl_xor(v1v, 1);
        float sq = q2 + __shfl_xor(q2, 1);
        if (dd == 0) {
          atomicAdd(&c.stats1[(t & 1) * 128 + bb * 2 + 0], s);
          atomicAdd(&c.stats1[(t & 1) * 128 + bb * 2 + 1], sq);
        }
      }
    }
    gridbar(c.leafs, c.root, ++ph);

    // ========== Phase5: gi2 GEMM (LN1-folded) + GRU2 + v2 + stats2 ==========
    {
      const int j = cslot >> 3, kz = cslot & 7;
      float acc[8] = {0.f, 0.f, 0.f, 0.f, 0.f, 0.f, 0.f, 0.f};
      if (j < 6) {
        const float* wbase = c.WB4 + (size_t)g * 4096 + cslot * 4;
        const float* xbase = c.v1 + kz * 64 + (size_t)(8 * r) * 512;
        for (int kk = 0; kk < 16; ++kk) {
          float4 w = *(const float4*)(wbase + kk * 256);
#pragma unroll
          for (int qq = 0; qq < 8; ++qq) {
            float4 x = *(const float4*)(xbase + qq * 512 + kk * 4);
            acc[qq] = fmaf(w.x, x.x, fmaf(w.y, x.y, fmaf(w.z, x.z, fmaf(w.w, x.w, acc[qq]))));
          }
        }
      }
#pragma unroll
      for (int qq = 0; qq < 8; ++qq) {
        acc[qq] += __shfl_xor(acc[qq], 1);
        acc[qq] += __shfl_xor(acc[qq], 2);
        acc[qq] += __shfl_xor(acc[qq], 4);
      }
      __syncthreads();
      if (kz == 0 && j < 6) {
#pragma unroll
        for (int qq = 0; qq < 8; ++qq) sm[j * 64 + 8 * r + qq] = acc[qq];
      }
      __syncthreads();
      if (tid < 128) {
        int bb = tid >> 1, dd = tid & 1, d = 2 * g + dd;
        const float* s1 = c.stats1 + (t & 1) * 128 + bb * 2;
        float m1 = s1[0] * (1.f / 512.f);
        float va = s1[1] * (1.f / 512.f) - m1 * m1;
        float i1 = rsqrtf(va + EPS);
        int c0 = d, c1 = 512 + d, c2 = 1024 + d;
        float gir = i1 * (sm[(0 + dd) * 64 + bb] - m1 * c.Sg[c0]) + c.cbg[c0];
        float giz = i1 * (sm[(2 + dd) * 64 + bb] - m1 * c.Sg[c1]) + c.cbg[c1];
        float gig = i1 * (sm[(4 + dd) * 64 + bb] - m1 * c.Sg[c2]) + c.cbg[c2];
        float hr = c.gh2g[bb * 1536 + d] + c.bhh2[d];
        float hz = c.gh2g[bb * 1536 + 512 + d] + c.bhh2[512 + d];
        float hg = c.gh2g[bb * 1536 + 1024 + d] + c.bhh2[1024 + d];
        float r2 = sigf(gir + hr);
        float z2 = sigf(giz + hz);
        float n2 = tanhf(gig + r2 * hg);
        float hold = c.h2[bb * 512 + d];
        float hnew = (1.f - z2) * n2 + z2 * hold;
        c.h2[bb * 512 + d] = (t < declenI[bb]) ? hnew : hold;
        float h1r = (c.v1[bb * 512 + d] - m1) * i1 * c.ln1g[d] + c.ln1b[d];
        float v2v = hnew + h1r;
        c.v2[bb * 512 + d] = v2v;
        float q2 = v2v * v2v;
        float s = v2v + __shfl_xor(v2v, 1);
        float sq = q2 + __shfl_xor(q2, 1);
        if (dd == 0) {
          atomicAdd(&c.stats2[(t & 1) * 128 + bb * 2 + 0], s);
          atomicAdd(&c.stats2[(t & 1) * 128 + bb * 2 + 1], sq);
        }
      }
    }
    gridbar(c.leafs, c.root, ++ph);
  }
}

extern "C" void kernel_launch(void* const* d_in, const int* in_sizes, int n_in,
                              void* d_out, int out_size, void* d_ws, size_t ws_size,
                              hipStream_t stream) {
  (void)in_sizes; (void)n_in; (void)ws_size;
  Ctx c;
  c.enc = (const float*)d_in[0];
  c.caps_in = (const int*)d_in[1];
  c.lens_in = (const int*)d_in[2];
  c.eaw = (const float*)d_in[3];
  c.eab = (const float*)d_in[4];
  c.daw = (const float*)d_in[5];
  c.dab = (const float*)d_in[6];
  c.faw = (const float*)d_in[7];
  c.fab = (const float*)d_in[8];
  c.gw1 = (const float*)d_in[9];
  c.gb1 = (const float*)d_in[10];
  c.gw2 = (const float*)d_in[11];
  c.gb2 = (const float*)d_in[12];
  c.emb = (const float*)d_in[13];
  c.wih1 = (const float*)d_in[14];
  c.whh1 = (const float*)d_in[15];
  c.bih1 = (const float*)d_in[16];
  c.bhh1 = (const float*)d_in[17];
  c.wih2 = (const float*)d_in[18];
  c.whh2 = (const float*)d_in[19];
  c.bih2 = (const float*)d_in[20];
  c.bhh2 = (const float*)d_in[21];
  c.projw = (const float*)d_in[22];
  c.projb = (const float*)d_in[23];
  c.ln1g = (const float*)d_in[24];
  c.ln1b = (const float*)d_in[25];
  c.ln2g = (const float*)d_in[26];
  c.ln2b = (const float*)d_in[27];
  c.fw1 = (const float*)d_in[28];
  c.fb1 = (const float*)d_in[29];
  c.fw2 = (const float*)d_in[30];
  c.fb2 = (const float*)d_in[31];
  c.out = (float*)d_out;

  char* wp_ = (char*)d_ws;
  auto alloc = [&](size_t bytes) -> char* {
    char* p = wp_;
    wp_ += (bytes + 255) & ~(size_t)255;
    return p;
  };
  // zero-region (one memset): barriers | h1 | h2 | stats1 | stats2
  char* zbase = wp_;
  c.leafs = (int*)alloc(256 * 4);   // 8 leaves at stride 32 ints
  c.root = (int*)alloc(256);
  c.h1 = (float*)alloc((size_t)B * 512 * 4);
  c.h2 = (float*)alloc((size_t)B * 512 * 4);
  c.stats1 = (float*)alloc(2 * 64 * 2 * 4);
  c.stats2 = (float*)alloc(2 * 64 * 2 * 4);
  size_t zbytes = (size_t)(wp_ - zbase);

  c.order_i = (int*)alloc(B * 4);
  c.declen = (int*)alloc(B * 4);
  c.caps_s = (int*)alloc((size_t)B * MAXLEN * 4);
  c.EaT = (float*)alloc((size_t)512 * 128 * 4);
  c.att1 = (float*)alloc((size_t)B * P * 128 * 4);
  c.v1 = (float*)alloc((size_t)B * 512 * 4);
  c.v2 = (float*)alloc((size_t)B * 512 * 4);
  c.gin = (float*)alloc((size_t)B * 768 * 4);
  c.fg = (float*)alloc((size_t)B * 1024 * 4);
  c.gh1g = (float*)alloc((size_t)B * 1536 * 4);
  c.gh2g = (float*)alloc((size_t)B * 1536 * 4);
  c.att2acc = (float*)alloc((size_t)B * 256 * 4);
  c.eP = (float*)alloc((size_t)B * 256 * 4);
  c.WB1 = (float*)alloc((size_t)256 * 8192 * 4);
  c.WB2 = (float*)alloc((size_t)256 * 8192 * 4);
  c.WB3 = (float*)alloc((size_t)256 * 6144 * 4);
  c.WB4 = (float*)alloc((size_t)256 * 4096 * 4);
  c.WtA2 = (float*)alloc((size_t)256 * 512 * 4);
  c.Sf = (float*)alloc(1024 * 4);
  c.cbf = (float*)alloc(1024 * 4);
  c.Sg = (float*)alloc(1536 * 4);
  c.cbg = (float*)alloc(1536 * 4);

  hipMemsetAsync(d_out, 0, (size_t)out_size * 4, stream);
  hipMemsetAsync(zbase, 0, zbytes, stream);

  k_order<<<1, 64, 0, stream>>>(c);
  k_caps<<<(B * MAXLEN + 255) / 256, 256, 0, stream>>>(c);
  k_eat<<<(128 * 512 + 255) / 256, 256, 0, stream>>>(c);
  k_att1<<<(B * P) / 8, 256, 0, stream>>>(c);
  k_wb1<<<256, 256, 0, stream>>>(c);
  k_wb2<<<256, 256, 0, stream>>>(c);
  k_wb3<<<256, 256, 0, stream>>>(c);
  k_wb4<<<256, 256, 0, stream>>>(c);
  k_wta2<<<512, 256, 0, stream>>>(c);
  k_consts<<<2560, 256, 0, stream>>>(c);

  persist<<<256, 512, 0, stream>>>(c);
}

// Round 4
// 41681.268 us; speedup vs baseline: 1.3906x; 1.3494x over previous
//
#include <hip/hip_runtime.h>
#include <math.h>

#define B 64
#define P 196
#define ENCD 512
#define DECD 512
#define EMBD 256
#define ATTD 128
#define FFND 1024
#define VV 2000
#define MAXLEN 160
#define TSTEPS 159
#define EPS 1e-5f

// output chunk offsets (flat f32)
#define OUT_PRED ((size_t)0)
#define OUT_CAPS ((size_t)(B * TSTEPS * VV))
#define OUT_DECL (OUT_CAPS + (size_t)(B * MAXLEN))
#define OUT_ALPH (OUT_DECL + (size_t)B)
#define OUT_ORDR (OUT_ALPH + (size_t)(B * TSTEPS * P))

struct Ctx {
  // inputs
  const float* enc; const int* caps_in; const int* lens_in;
  const float* eaw; const float* eab; const float* daw; const float* dab;
  const float* faw; const float* fab;
  const float* gw1; const float* gb1; const float* gw2; const float* gb2;
  const float* emb;
  const float* wih1; const float* whh1; const float* bih1; const float* bhh1;
  const float* wih2; const float* whh2; const float* bih2; const float* bhh2;
  const float* projw; const float* projb;
  const float* ln1g; const float* ln1b; const float* ln2g; const float* ln2b;
  const float* fw1; const float* fb1; const float* fw2; const float* fb2;
  // ws
  int* leafs; int* root;
  int* order_i; int* declen; int* caps_s;
  float* EaT; float* att1;
  float* h1; float* h2; float* v1; float* v2;
  float* gin; float* fgr; float* gh1g; float* gh2g;
  float* att2acc; float* eP;
  float* stats1; float* stats2;   // [2][64][2]
  float* WP1; float* WP2; float* WP3; float* WP4;
  float* Sf; float* cbf; float* Sg; float* cbg;
  float* out;
};

__device__ __forceinline__ float sigf(float x) { return 1.f / (1.f + __expf(-x)); }

// ---- coherent (MALL-level) access helpers: relaxed agent atomics => sc1 ops,
// ---- NO cache maintenance instructions (keeps weights resident in L2).
__device__ __forceinline__ unsigned long long ld8(const float* p) {
  return __hip_atomic_load((unsigned long long*)p, __ATOMIC_RELAXED, __HIP_MEMORY_SCOPE_AGENT);
}
__device__ __forceinline__ float ld4(const float* p) {
  unsigned int u = __hip_atomic_load((unsigned int*)p, __ATOMIC_RELAXED, __HIP_MEMORY_SCOPE_AGENT);
  return __uint_as_float(u);
}
__device__ __forceinline__ void st4(float* p, float v) {
  __hip_atomic_store((unsigned int*)p, __float_as_uint(v), __ATOMIC_RELAXED, __HIP_MEMORY_SCOPE_AGENT);
}
__device__ __forceinline__ void atomF(float* p, float v) {
  __hip_atomic_fetch_add(p, v, __ATOMIC_RELAXED, __HIP_MEMORY_SCOPE_AGENT);
}

// ---------------- setup kernels ----------------

__global__ void k_order(Ctx c) {
  __shared__ int lens[B];
  int tid = threadIdx.x;
  lens[tid] = c.lens_in[tid];
  __syncthreads();
  int li = lens[tid];
  int pos = 0;
  for (int j = 0; j < B; ++j) {
    int lj = lens[j];
    pos += (lj > li || (lj == li && j < tid)) ? 1 : 0;
  }
  c.order_i[pos] = tid;
  c.declen[pos] = li - 1;
  c.out[OUT_ORDR + pos] = (float)tid;
  c.out[OUT_DECL + pos] = (float)(li - 1);
}

__global__ __launch_bounds__(256) void k_caps(Ctx c) {
  int idx = blockIdx.x * 256 + threadIdx.x;
  if (idx < B * MAXLEN) {
    int b = idx / MAXLEN, t = idx - b * MAXLEN;
    int v = c.caps_in[c.order_i[b] * MAXLEN + t];
    c.caps_s[idx] = v;
    c.out[OUT_CAPS + idx] = (float)v;
  }
}

__global__ __launch_bounds__(256) void k_eat(Ctx c) {
  int idx = blockIdx.x * 256 + threadIdx.x;
  if (idx < 128 * 512) {
    int k = idx >> 7, d = idx & 127;
    c.EaT[(size_t)k * 128 + d] = c.eaw[(size_t)d * 512 + k];
  }
}

// att1[(b*P+p)*128 + d] = sum_k enc[ob,p,k]*eaw[d,k]  (no bias)
__global__ __launch_bounds__(256) void k_att1(Ctx c) {
  __shared__ float Xs[8 * 512];
  int tid = threadIdx.x;
  int r0 = blockIdx.x * 8;
  for (int idx = tid; idx < 8 * 512; idx += 256) {
    int rr = idx >> 9, k = idx & 511;
    int r = r0 + rr;
    int b = r / P, p = r - b * P;
    int ob = c.order_i[b];
    Xs[idx] = c.enc[((size_t)(ob * P + p)) * ENCD + k];
  }
  __syncthreads();
  int d = tid >> 1, kh = tid & 1;
  float acc[8];
#pragma unroll
  for (int rr = 0; rr < 8; ++rr) acc[rr] = 0.f;
  int kbase = kh * 256;
  for (int k = 0; k < 256; ++k) {
    float w = c.EaT[(size_t)(kbase + k) * 128 + d];
#pragma unroll
    for (int rr = 0; rr < 8; ++rr) acc[rr] = fmaf(w, Xs[rr * 512 + kbase + k], acc[rr]);
  }
#pragma unroll
  for (int rr = 0; rr < 8; ++rr) {
    acc[rr] += __shfl_xor(acc[rr], 1);
    if (kh == 0) c.att1[(size_t)(r0 + rr) * 128 + d] = acc[rr];
  }
}

// WP1: 68 cgs x 64 cols, K=512. float idx = (cg*128+kk)*256 + cl*4 + i
// unified cols: [0,1536) gh1/whh1; [1536,3072) gh2/whh2; [3072,3328) att2(daw)+gate1(gw1);
// [3328,4352) fg = ln2g-folded fw1
__global__ __launch_bounds__(256) void k_wp1(Ctx c) {
  int cg = blockIdx.x;
  float* dst = c.WP1 + (size_t)cg * 32768;
  for (int idx = threadIdx.x; idx < 32768; idx += 256) {
    int kk = idx >> 8, cl = (idx >> 2) & 63, i = idx & 3;
    int k = kk * 4 + i;
    int ucol = cg * 64 + cl;
    float v;
    if (ucol < 1536) v = c.whh1[(size_t)ucol * 512 + k];
    else if (ucol < 3072) v = c.whh2[(size_t)(ucol - 1536) * 512 + k];
    else if (ucol < 3328) {
      int a2 = ucol - 3072;
      v = (a2 < 128) ? c.daw[(size_t)a2 * 512 + k] : c.gw1[(size_t)(a2 - 128) * 512 + k];
    } else v = c.ln2g[k] * c.fw1[(size_t)(ucol - 3328) * 512 + k];
    dst[idx] = v;
  }
}

// WP2: preds, 64 cgs x 32 cols, K=1024. float idx = (cg*256+kk)*128 + cl*4 + i
__global__ __launch_bounds__(256) void k_wp2(Ctx c) {
  int cg = blockIdx.x;
  float* dst = c.WP2 + (size_t)cg * 32768;
  for (int idx = threadIdx.x; idx < 32768; idx += 256) {
    int kk = idx >> 7, cl = (idx >> 2) & 31, i = idx & 3;
    int k = kk * 4 + i;
    int col = cg * 32 + cl;
    dst[idx] = (col < VV) ? c.fw2[(size_t)col * 1024 + k] : 0.f;
  }
}

// WP3: giP, 64 cgs x 32 cols (u = d*4+comp; comp0..2=wih1 r/z/n, comp3=proj), K=768
__global__ __launch_bounds__(256) void k_wp3(Ctx c) {
  int cg = blockIdx.x;
  float* dst = c.WP3 + (size_t)cg * 24576;
  for (int idx = threadIdx.x; idx < 24576; idx += 256) {
    int kk = idx >> 7, cl = (idx >> 2) & 31, i = idx & 3;
    int k = kk * 4 + i;
    int u = cg * 32 + cl;
    int d = u >> 2, comp = u & 3;
    dst[idx] = (comp < 3) ? c.wih1[(size_t)(comp * 512 + d) * 768 + k]
                          : c.projw[(size_t)d * 768 + k];
  }
}

// WP4: gi2 (ln1g-folded wih2), 64 cgs x 32 cols (cl = dloc*4+comp, comp<3 real), K=512
__global__ __launch_bounds__(256) void k_wp4(Ctx c) {
  int cg = blockIdx.x;
  float* dst = c.WP4 + (size_t)cg * 16384;
  for (int idx = threadIdx.x; idx < 16384; idx += 256) {
    int kk = idx >> 7, cl = (idx >> 2) & 31, i = idx & 3;
    int k = kk * 4 + i;
    int dloc = cl >> 2, comp = cl & 3;
    int d = cg * 8 + dloc;
    dst[idx] = (comp < 3) ? c.ln1g[k] * c.wih2[(size_t)(comp * 512 + d) * 512 + k] : 0.f;
  }
}

// Sf/cbf (1024) and Sg/cbg (1536)
__global__ __launch_bounds__(256) void k_consts(Ctx c) {
  __shared__ float r1[256], r2[256];
  int i = blockIdx.x, tid = threadIdx.x;
  float a = 0.f, b2 = 0.f;
  if (i < 1024) {
    const float* w = c.fw1 + (size_t)i * 512;
    for (int k = tid; k < 512; k += 256) { a = fmaf(c.ln2g[k], w[k], a); b2 = fmaf(c.ln2b[k], w[k], b2); }
  } else {
    const float* w = c.wih2 + (size_t)(i - 1024) * 512;
    for (int k = tid; k < 512; k += 256) { a = fmaf(c.ln1g[k], w[k], a); b2 = fmaf(c.ln1b[k], w[k], b2); }
  }
  r1[tid] = a; r2[tid] = b2;
  __syncthreads();
  for (int s = 128; s > 0; s >>= 1) {
    if (tid < s) { r1[tid] += r1[tid + s]; r2[tid] += r2[tid + s]; }
    __syncthreads();
  }
  if (tid == 0) {
    if (i < 1024) { c.Sf[i] = r1[0]; c.cbf[i] = r2[0] + c.fb1[i]; }
    else { c.Sg[i - 1024] = r1[0]; c.cbg[i - 1024] = r2[0] + c.bih2[i - 1024]; }
  }
}

// ---------------- persistent kernel ----------------

// Relaxed barrier: NO fences. __syncthreads drains each wave's vmcnt(0); coherent
// (sc1) stores are MALL-visible once acked, so flag-after-drain is sufficient.
__device__ __forceinline__ void gridbar(int* leafs, int* root, int ph) {
  __syncthreads();
  if (threadIdx.x == 0) {
    __builtin_amdgcn_s_waitcnt(0);
    int leaf = (blockIdx.x & 7) * 32;
    int old = __hip_atomic_fetch_add(&leafs[leaf], 1, __ATOMIC_RELAXED, __HIP_MEMORY_SCOPE_AGENT);
    if (old == ph * 32 - 1)
      __hip_atomic_fetch_add(root, 1, __ATOMIC_RELAXED, __HIP_MEMORY_SCOPE_AGENT);
    while (__hip_atomic_load(root, __ATOMIC_RELAXED, __HIP_MEMORY_SCOPE_AGENT) < ph * 8)
      __builtin_amdgcn_s_sleep(2);
  }
  __syncthreads();
}

__global__ __launch_bounds__(512, 2) void persist(Ctx c) {
  __shared__ float XS[8192];      // X staging (16 rows x <=512 floats) / phase3 scratch
  __shared__ float RED[4096];     // k-split partials
  __shared__ float FIN[1024];     // reduced GEMM outputs / gate scratch
  __shared__ float att2sL[128];
  __shared__ float constL[392];
  __shared__ float sstat[64];     // [0..31] stats2 m/i (phase1); [32..63] stats1 m/i (phase5)
  __shared__ int declenI[64];
  __shared__ float gateS_sh;
  const int g = blockIdx.x;
  const int tid = threadIdx.x;
  const int b = g >> 2, q = g & 3;        // attention mapping
  const int cg = g & 63, rg = g >> 6;     // GEMM mapping (XCD-local weight slices)
  const int cl32 = tid & 31, kl8 = (tid >> 5) & 7;
  const int cl64 = tid & 63, kl4 = (tid >> 6) & 3;
  const int rl = tid >> 8;                // 0..1, rows rl*8..+8 of the 16
  const int el = tid & 127, pb = tid >> 7;

  if (tid < 128) {
    constL[tid] = c.faw[tid];
    constL[128 + tid] = c.dab[tid] + c.eab[tid];
    constL[256 + tid] = c.gb1[tid];
  }
  if (tid == 0) { constL[384] = c.gb2[0]; constL[385] = c.fab[0]; }
  if (tid < 64) declenI[tid] = c.declen[tid];
  float encR[49];  // enc[b, pb*49+i, q*128+el]
  {
    const int ob = c.order_i[b];
    const float* ep = c.enc + ((size_t)(ob * P) + (size_t)pb * 49) * ENCD + q * 128 + el;
#pragma unroll
    for (int i = 0; i < 49; ++i) encR[i] = ep[(size_t)i * ENCD];
  }
  __syncthreads();

  int ph = 0;
  for (int t = 0; t < MAXLEN; ++t) {
    // ===== PHASE1: gh1 | gh2 | att2/gate1 | fg(LN2-folded, relu) ===============
    {
      const int slot2 = (t + 1) & 1;
      const int njob = (g < 16) ? 2 : 1;
      for (int jb = 0; jb < njob; ++jb) {
        int jcg, jrg;
        if (jb == 0) { jcg = cg; jrg = rg; }
        else { jcg = 64 + (g & 3); jrg = g >> 2; }
        const float* X = (jcg < 24) ? c.h1 : (jcg < 52 ? c.h2 : c.v2);
        const int r0 = jrg * 16;
        __syncthreads();
        if (jcg >= 52 && tid < 16) {
          float s0 = ld4(c.stats2 + slot2 * 128 + (r0 + tid) * 2);
          float s1v = ld4(c.stats2 + slot2 * 128 + (r0 + tid) * 2 + 1);
          float m = s0 * (1.f / 512.f);
          float va = s1v * (1.f / 512.f) - m * m;
          sstat[tid] = m; sstat[16 + tid] = rsqrtf(va + EPS);
        }
        for (int idx = tid; idx < 4096; idx += 512) {
          int row = idx >> 8, off = (idx & 255) * 2;
          *(unsigned long long*)(XS + row * 512 + off) = ld8(X + (size_t)(r0 + row) * 512 + off);
        }
        __syncthreads();
        float acc[8] = {0.f, 0.f, 0.f, 0.f, 0.f, 0.f, 0.f, 0.f};
        const float4* wp = (const float4*)c.WP1 + ((size_t)jcg * 128 + kl4 * 32) * 64 + cl64;
        const float* xb = XS + rl * 8 * 512 + kl4 * 128;
        for (int u = 0; u < 32; ++u) {
          float4 w = wp[(size_t)u * 64];
#pragma unroll
          for (int rr = 0; rr < 8; ++rr) {
            float4 x = *(const float4*)(xb + rr * 512 + u * 4);
            acc[rr] = fmaf(w.x, x.x, fmaf(w.y, x.y, fmaf(w.z, x.z, fmaf(w.w, x.w, acc[rr]))));
          }
        }
#pragma unroll
        for (int rr = 0; rr < 8; ++rr) RED[(kl4 * 16 + rl * 8 + rr) * 64 + cl64] = acc[rr];
        __syncthreads();
#pragma unroll
        for (int oo = 0; oo < 2; ++oo) {
          int o = tid + oo * 512;
          int row = o >> 6, col = o & 63;
          float s = RED[row * 64 + col] + RED[1024 + row * 64 + col] +
                    RED[2048 + row * 64 + col] + RED[3072 + row * 64 + col];
          int ucol = jcg * 64 + col;
          int bb = r0 + row;
          if (ucol < 1536) st4(c.gh1g + bb * 1536 + ucol, s);
          else if (ucol < 3072) st4(c.gh2g + bb * 1536 + (ucol - 1536), s);
          else if (ucol < 3328) st4(c.att2acc + bb * 256 + (ucol - 3072), s);
          else {
            int cf = ucol - 3328;
            float v = sstat[16 + row] * (s - sstat[row] * c.Sf[cf]) + c.cbf[cf];
            st4(c.fgr + bb * 1024 + cf, fmaxf(v, 0.f));
          }
        }
      }
    }
    gridbar(c.leafs, c.root, ++ph);

    // ===== PHASE2: preds GEMM (store t-1) + stats zero + gate + e-partials =====
    {
      if (g == 0) {
        int sl = t & 1;
        if (tid < 128) st4(c.stats1 + sl * 128 + tid, 0.f);
        else if (tid < 256) st4(c.stats2 + sl * 128 + (tid - 128), 0.f);
      }
      const int r0 = rg * 16;
      float acc[8] = {0.f, 0.f, 0.f, 0.f, 0.f, 0.f, 0.f, 0.f};
      for (int ck = 0; ck < 2; ++ck) {
        __syncthreads();
        for (int idx = tid; idx < 4096; idx += 512) {
          int row = idx >> 8, off = (idx & 255) * 2;
          *(unsigned long long*)(XS + row * 512 + off) =
              ld8(c.fgr + (size_t)(r0 + row) * 1024 + ck * 512 + off);
        }
        __syncthreads();
        const float4* wp = (const float4*)c.WP2 + ((size_t)cg * 256 + ck * 128 + kl8 * 16) * 32 + cl32;
        const float* xb = XS + rl * 8 * 512 + kl8 * 64;
        for (int u = 0; u < 16; ++u) {
          float4 w = wp[(size_t)u * 32];
#pragma unroll
          for (int rr = 0; rr < 8; ++rr) {
            float4 x = *(const float4*)(xb + rr * 512 + u * 4);
            acc[rr] = fmaf(w.x, x.x, fmaf(w.y, x.y, fmaf(w.z, x.z, fmaf(w.w, x.w, acc[rr]))));
          }
        }
      }
#pragma unroll
      for (int rr = 0; rr < 8; ++rr) RED[(kl8 * 16 + rl * 8 + rr) * 32 + cl32] = acc[rr];
      __syncthreads();
      {
        int row = tid >> 5, col = tid & 31;
        float s = 0.f;
#pragma unroll
        for (int kl = 0; kl < 8; ++kl) s += RED[(kl * 16 + row) * 32 + col];
        int vcol = cg * 32 + col, bb = r0 + row;
        if (t > 0 && vcol < VV && (t - 1) < declenI[bb])
          c.out[OUT_PRED + ((size_t)bb * TSTEPS + (t - 1)) * VV + vcol] = s + c.fb2[vcol];
      }
      __syncthreads();
      if (tid < 128) {
        att2sL[tid] = ld4(c.att2acc + b * 256 + tid) + constL[128 + tid];
        float g1 = fmaxf(ld4(c.att2acc + b * 256 + 128 + tid) + constL[256 + tid], 0.f);
        FIN[tid] = g1 * c.gw2[tid];
      }
      __syncthreads();
      for (int s2 = 64; s2 > 0; s2 >>= 1) {
        if (tid < s2) FIN[tid] += FIN[tid + s2];
        __syncthreads();
      }
      if (tid == 0) gateS_sh = sigf(FIN[0] + constL[384]);
      {
        int pg = tid >> 3, jl = tid & 7;
        float e = 0.f;
        if (pg < 49) {
          const float* a1p = c.att1 + ((size_t)b * P + 49 * q + pg) * 128 + jl * 16;
#pragma unroll
          for (int jj = 0; jj < 16; ++jj)
            e = fmaf(fmaxf(a1p[jj] + att2sL[jl * 16 + jj], 0.f), constL[jl * 16 + jj], e);
        }
        e += __shfl_xor(e, 1); e += __shfl_xor(e, 2); e += __shfl_xor(e, 4);
        if (jl == 0 && pg < 49) st4(c.eP + b * 256 + 49 * q + pg, e + constL[385]);
      }
    }
    gridbar(c.leafs, c.root, ++ph);

    // ===== PHASE3: softmax + alpha out + awe(register enc) + gin ===============
    {
      float ev = -3.0e38f;
      if (tid < P) ev = ld4(c.eP + b * 256 + tid);
      XS[tid] = ev;
      __syncthreads();
      for (int s2 = 256; s2 > 0; s2 >>= 1) {
        if (tid < s2) XS[tid] = fmaxf(XS[tid], XS[tid + s2]);
        __syncthreads();
      }
      float mx = XS[0];
      __syncthreads();
      float ex = (tid < P) ? __expf(ev - mx) : 0.f;
      XS[tid] = ex;
      __syncthreads();
      for (int s2 = 256; s2 > 0; s2 >>= 1) {
        if (tid < s2) XS[tid] += XS[tid + s2];
        __syncthreads();
      }
      float al = ex / XS[0];
      XS[512 + tid] = al;
      __syncthreads();
      if (tid < P && t < declenI[b])
        c.out[OUT_ALPH + ((size_t)b * TSTEPS + t) * P + tid] = al;
      float s_ = 0.f;
#pragma unroll
      for (int i = 0; i < 49; ++i) s_ = fmaf(XS[512 + pb * 49 + i], encR[i], s_);
      XS[1024 + tid] = s_;
      __syncthreads();
      if (tid < 128) {
        float tot = XS[1024 + tid] + XS[1152 + tid] + XS[1280 + tid] + XS[1408 + tid];
        st4(c.gin + b * 768 + 256 + q * 128 + tid, tot * gateS_sh);
      }
      if (q == 1 && tid < 256) {
        int tok = c.caps_s[b * MAXLEN + t];
        st4(c.gin + b * 768 + tid, c.emb[(size_t)tok * 256 + tid]);
      }
    }
    gridbar(c.leafs, c.root, ++ph);

    // ===== PHASE4: giP GEMM + GRU1 + v1 + stats1 ===============================
    {
      const int r0 = rg * 16;
      float acc[8] = {0.f, 0.f, 0.f, 0.f, 0.f, 0.f, 0.f, 0.f};
      __syncthreads();
      for (int idx = tid; idx < 4096; idx += 512) {
        int row = idx >> 8, off = (idx & 255) * 2;
        *(unsigned long long*)(XS + row * 512 + off) = ld8(c.gin + (size_t)(r0 + row) * 768 + off);
      }
      __syncthreads();
      {
        const float4* wp = (const float4*)c.WP3 + ((size_t)cg * 192 + kl8 * 16) * 32 + cl32;
        const float* xb = XS + rl * 8 * 512 + kl8 * 64;
        for (int u = 0; u < 16; ++u) {
          float4 w = wp[(size_t)u * 32];
#pragma unroll
          for (int rr = 0; rr < 8; ++rr) {
            float4 x = *(const float4*)(xb + rr * 512 + u * 4);
            acc[rr] = fmaf(w.x, x.x, fmaf(w.y, x.y, fmaf(w.z, x.z, fmaf(w.w, x.w, acc[rr]))));
          }
        }
      }
      __syncthreads();
      for (int idx = tid; idx < 2048; idx += 512) {
        int row = idx >> 7, off = (idx & 127) * 2;
        *(unsigned long long*)(XS + row * 256 + off) =
            ld8(c.gin + (size_t)(r0 + row) * 768 + 512 + off);
      }
      __syncthreads();
      {
        const float4* wp = (const float4*)c.WP3 + ((size_t)cg * 192 + 128 + kl8 * 8) * 32 + cl32;
        const float* xb = XS + rl * 8 * 256 + kl8 * 32;
        for (int u = 0; u < 8; ++u) {
          float4 w = wp[(size_t)u * 32];
#pragma unroll
          for (int rr = 0; rr < 8; ++rr) {
            float4 x = *(const float4*)(xb + rr * 256 + u * 4);
            acc[rr] = fmaf(w.x, x.x, fmaf(w.y, x.y, fmaf(w.z, x.z, fmaf(w.w, x.w, acc[rr]))));
          }
        }
      }
#pragma unroll
      for (int rr = 0; rr < 8; ++rr) RED[(kl8 * 16 + rl * 8 + rr) * 32 + cl32] = acc[rr];
      __syncthreads();
      {
        int row = tid >> 5, col = tid & 31;
        float s = 0.f;
#pragma unroll
        for (int kl = 0; kl < 8; ++kl) s += RED[(kl * 16 + row) * 32 + col];
        FIN[tid] = s;
      }
      __syncthreads();
      if (tid < 128) {
        int row = tid >> 3, dloc = tid & 7;
        int bb = r0 + row, d = cg * 8 + dloc;
        float gir = FIN[row * 32 + dloc * 4 + 0] + c.bih1[d];
        float giz = FIN[row * 32 + dloc * 4 + 1] + c.bih1[512 + d];
        float gig = FIN[row * 32 + dloc * 4 + 2] + c.bih1[1024 + d];
        float pj = FIN[row * 32 + dloc * 4 + 3] + c.projb[d];
        float hr = ld4(c.gh1g + bb * 1536 + d) + c.bhh1[d];
        float hz = ld4(c.gh1g + bb * 1536 + 512 + d) + c.bhh1[512 + d];
        float hg = ld4(c.gh1g + bb * 1536 + 1024 + d) + c.bhh1[1024 + d];
        float r_ = sigf(gir + hr);
        float z_ = sigf(giz + hz);
        float n_ = tanhf(gig + r_ * hg);
        float hold = ld4(c.h1 + bb * 512 + d);
        float hnew = (1.f - z_) * n_ + z_ * hold;
        st4(c.h1 + bb * 512 + d, (t < declenI[bb]) ? hnew : hold);
        float v1v = hnew + pj;
        st4(c.v1 + bb * 512 + d, v1v);
        float ss = v1v, sq = v1v * v1v;
        ss += __shfl_xor(ss, 1); ss += __shfl_xor(ss, 2); ss += __shfl_xor(ss, 4);
        sq += __shfl_xor(sq, 1); sq += __shfl_xor(sq, 2); sq += __shfl_xor(sq, 4);
        if (dloc == 0) {
          atomF(c.stats1 + (t & 1) * 128 + bb * 2, ss);
          atomF(c.stats1 + (t & 1) * 128 + bb * 2 + 1, sq);
        }
      }
    }
    gridbar(c.leafs, c.root, ++ph);

    // ===== PHASE5: gi2 GEMM (LN1-folded) + GRU2 + v2 + stats2 ==================
    {
      const int r0 = rg * 16;
      if (tid < 16) {
        float s0 = ld4(c.stats1 + (t & 1) * 128 + (r0 + tid) * 2);
        float s1v = ld4(c.stats1 + (t & 1) * 128 + (r0 + tid) * 2 + 1);
        float m = s0 * (1.f / 512.f);
        float va = s1v * (1.f / 512.f) - m * m;
        sstat[32 + tid] = m; sstat[48 + tid] = rsqrtf(va + EPS);
      }
      for (int idx = tid; idx < 4096; idx += 512) {
        int row = idx >> 8, off = (idx & 255) * 2;
        *(unsigned long long*)(XS + row * 512 + off) = ld8(c.v1 + (size_t)(r0 + row) * 512 + off);
      }
      __syncthreads();
      float acc[8] = {0.f, 0.f, 0.f, 0.f, 0.f, 0.f, 0.f, 0.f};
      {
        const float4* wp = (const float4*)c.WP4 + ((size_t)cg * 128 + kl8 * 16) * 32 + cl32;
        const float* xb = XS + rl * 8 * 512 + kl8 * 64;
        for (int u = 0; u < 16; ++u) {
          float4 w = wp[(size_t)u * 32];
#pragma unroll
          for (int rr = 0; rr < 8; ++rr) {
            float4 x = *(const float4*)(xb + rr * 512 + u * 4);
            acc[rr] = fmaf(w.x, x.x, fmaf(w.y, x.y, fmaf(w.z, x.z, fmaf(w.w, x.w, acc[rr]))));
          }
        }
      }
#pragma unroll
      for (int rr = 0; rr < 8; ++rr) RED[(kl8 * 16 + rl * 8 + rr) * 32 + cl32] = acc[rr];
      __syncthreads();
      {
        int row = tid >> 5, col = tid & 31;
        float s = 0.f;
#pragma unroll
        for (int kl = 0; kl < 8; ++kl) s += RED[(kl * 16 + row) * 32 + col];
        FIN[tid] = s;
      }
      __syncthreads();
      if (tid < 128) {
        int row = tid >> 3, dloc = tid & 7;
        int bb = r0 + row, d = cg * 8 + dloc;
        float m1 = sstat[32 + row], i1 = sstat[48 + row];
        float gir = i1 * (FIN[row * 32 + dloc * 4 + 0] - m1 * c.Sg[d]) + c.cbg[d];
        float giz = i1 * (FIN[row * 32 + dloc * 4 + 1] - m1 * c.Sg[512 + d]) + c.cbg[512 + d];
        float gig = i1 * (FIN[row * 32 + dloc * 4 + 2] - m1 * c.Sg[1024 + d]) + c.cbg[1024 + d];
        float hr = ld4(c.gh2g + bb * 1536 + d) + c.bhh2[d];
        float hz = ld4(c.gh2g + bb * 1536 + 512 + d) + c.bhh2[512 + d];
        float hg = ld4(c.gh2g + bb * 1536 + 1024 + d) + c.bhh2[1024 + d];
        float r_ = sigf(gir + hr);
        float z_ = sigf(giz + hz);
        float n_ = tanhf(gig + r_ * hg);
        float hold = ld4(c.h2 + bb * 512 + d);
        float hnew = (1.f - z_) * n_ + z_ * hold;
        st4(c.h2 + bb * 512 + d, (t < declenI[bb]) ? hnew : hold);
        float h1r = (XS[row * 512 + d] - m1) * i1 * c.ln1g[d] + c.ln1b[d];
        float v2v = hnew + h1r;
        st4(c.v2 + bb * 512 + d, v2v);
        float ss = v2v, sq = v2v * v2v;
        ss += __shfl_xor(ss, 1); ss += __shfl_xor(ss, 2); ss += __shfl_xor(ss, 4);
        sq += __shfl_xor(sq, 1); sq += __shfl_xor(sq, 2); sq += __shfl_xor(sq, 4);
        if (dloc == 0) {
          atomF(c.stats2 + (t & 1) * 128 + bb * 2, ss);
          atomF(c.stats2 + (t & 1) * 128 + bb * 2 + 1, sq);
        }
      }
    }
    gridbar(c.leafs, c.root, ++ph);
  }
}

extern "C" void kernel_launch(void* const* d_in, const int* in_sizes, int n_in,
                              void* d_out, int out_size, void* d_ws, size_t ws_size,
                              hipStream_t stream) {
  (void)in_sizes; (void)n_in; (void)ws_size;
  Ctx c;
  c.enc = (const float*)d_in[0];
  c.caps_in = (const int*)d_in[1];
  c.lens_in = (const int*)d_in[2];
  c.eaw = (const float*)d_in[3];
  c.eab = (const float*)d_in[4];
  c.daw = (const float*)d_in[5];
  c.dab = (const float*)d_in[6];
  c.faw = (const float*)d_in[7];
  c.fab = (const float*)d_in[8];
  c.gw1 = (const float*)d_in[9];
  c.gb1 = (const float*)d_in[10];
  c.gw2 = (const float*)d_in[11];
  c.gb2 = (const float*)d_in[12];
  c.emb = (const float*)d_in[13];
  c.wih1 = (const float*)d_in[14];
  c.whh1 = (const float*)d_in[15];
  c.bih1 = (const float*)d_in[16];
  c.bhh1 = (const float*)d_in[17];
  c.wih2 = (const float*)d_in[18];
  c.whh2 = (const float*)d_in[19];
  c.bih2 = (const float*)d_in[20];
  c.bhh2 = (const float*)d_in[21];
  c.projw = (const float*)d_in[22];
  c.projb = (const float*)d_in[23];
  c.ln1g = (const float*)d_in[24];
  c.ln1b = (const float*)d_in[25];
  c.ln2g = (const float*)d_in[26];
  c.ln2b = (const float*)d_in[27];
  c.fw1 = (const float*)d_in[28];
  c.fb1 = (const float*)d_in[29];
  c.fw2 = (const float*)d_in[30];
  c.fb2 = (const float*)d_in[31];
  c.out = (float*)d_out;

  char* wp_ = (char*)d_ws;
  auto alloc = [&](size_t bytes) -> char* {
    char* p = wp_;
    wp_ += (bytes + 255) & ~(size_t)255;
    return p;
  };
  // zero-region (one memset): barriers | h1 | h2 | stats1 | stats2
  char* zbase = wp_;
  c.leafs = (int*)alloc(256 * 4);
  c.root = (int*)alloc(256);
  c.h1 = (float*)alloc((size_t)B * 512 * 4);
  c.h2 = (float*)alloc((size_t)B * 512 * 4);
  c.stats1 = (float*)alloc(2 * 64 * 2 * 4);
  c.stats2 = (float*)alloc(2 * 64 * 2 * 4);
  size_t zbytes = (size_t)(wp_ - zbase);

  c.order_i = (int*)alloc(B * 4);
  c.declen = (int*)alloc(B * 4);
  c.caps_s = (int*)alloc((size_t)B * MAXLEN * 4);
  c.EaT = (float*)alloc((size_t)512 * 128 * 4);
  c.att1 = (float*)alloc((size_t)B * P * 128 * 4);
  c.v1 = (float*)alloc((size_t)B * 512 * 4);
  c.v2 = (float*)alloc((size_t)B * 512 * 4);
  c.gin = (float*)alloc((size_t)B * 768 * 4);
  c.fgr = (float*)alloc((size_t)B * 1024 * 4);
  c.gh1g = (float*)alloc((size_t)B * 1536 * 4);
  c.gh2g = (float*)alloc((size_t)B * 1536 * 4);
  c.att2acc = (float*)alloc((size_t)B * 256 * 4);
  c.eP = (float*)alloc((size_t)B * 256 * 4);
  c.WP1 = (float*)alloc((size_t)68 * 32768 * 4);
  c.WP2 = (float*)alloc((size_t)64 * 32768 * 4);
  c.WP3 = (float*)alloc((size_t)64 * 24576 * 4);
  c.WP4 = (float*)alloc((size_t)64 * 16384 * 4);
  c.Sf = (float*)alloc(1024 * 4);
  c.cbf = (float*)alloc(1024 * 4);
  c.Sg = (float*)alloc(1536 * 4);
  c.cbg = (float*)alloc(1536 * 4);

  hipMemsetAsync(d_out, 0, (size_t)out_size * 4, stream);
  hipMemsetAsync(zbase, 0, zbytes, stream);

  k_order<<<1, 64, 0, stream>>>(c);
  k_caps<<<(B * MAXLEN + 255) / 256, 256, 0, stream>>>(c);
  k_eat<<<(128 * 512 + 255) / 256, 256, 0, stream>>>(c);
  k_att1<<<(B * P) / 8, 256, 0, stream>>>(c);
  k_wp1<<<68, 256, 0, stream>>>(c);
  k_wp2<<<64, 256, 0, stream>>>(c);
  k_wp3<<<64, 256, 0, stream>>>(c);
  k_wp4<<<64, 256, 0, stream>>>(c);
  k_consts<<<2560, 256, 0, stream>>>(c);

  persist<<<256, 512, 0, stream>>>(c);
}

// Round 5
// 20695.024 us; speedup vs baseline: 2.8008x; 2.0141x over previous
//
#include <hip/hip_runtime.h>
#include <math.h>

#define B 64
#define P 196
#define ENCD 512
#define DECD 512
#define EMBD 256
#define ATTD 128
#define FFND 1024
#define VV 2000
#define MAXLEN 160
#define TSTEPS 159
#define EPS 1e-5f

// output chunk offsets (flat f32)
#define OUT_PRED ((size_t)0)
#define OUT_CAPS ((size_t)(B * TSTEPS * VV))
#define OUT_DECL (OUT_CAPS + (size_t)(B * MAXLEN))
#define OUT_ALPH (OUT_DECL + (size_t)B)
#define OUT_ORDR (OUT_ALPH + (size_t)(B * TSTEPS * P))

// per-cg column counts (D=8 col-groups)
#define P1C 544   // 192 whh1 | 192 whh2 | 32 att | 128 fg
#define P2C 250
#define P3C 256   // u = d*4+comp (r,z,n,proj), d in [cg*64, cg*64+64)
#define P4C 192   // u = d*3+comp (r,z,n),    d in [cg*64, cg*64+64)

struct Ctx {
  const float* enc; const int* caps_in; const int* lens_in;
  const float* eaw; const float* eab; const float* daw; const float* dab;
  const float* faw; const float* fab;
  const float* gw1; const float* gb1; const float* gw2; const float* gb2;
  const float* emb;
  const float* wih1; const float* whh1; const float* bih1; const float* bhh1;
  const float* wih2; const float* whh2; const float* bih2; const float* bhh2;
  const float* projw; const float* projb;
  const float* ln1g; const float* ln1b; const float* ln2g; const float* ln2b;
  const float* fw1; const float* fb1; const float* fw2; const float* fb2;
  // ws
  int* leafs; int* root;
  int* order_i; int* declen; int* caps_s;
  float* EaT; float* att1;
  float* h1; float* h2; float* v1; float* v2;
  float* gin; float* fgr; float* gh1g; float* gh2g; float* att2acc;
  float* stats1; float* stats2;   // [2][64][2]
  float* WP1; float* WP2; float* WP3; float* WP4;
  float* Sf; float* cbf; float* Sg; float* cbg;
  float* out;
};

__device__ __forceinline__ float sigf(float x) { return 1.f / (1.f + __expf(-x)); }

// ---- device-coherent (MALL) helpers: relaxed agent atomics => sc1, no cache flushes
__device__ __forceinline__ float ld4(const float* p) {
  unsigned int u = __hip_atomic_load((const unsigned int*)p, __ATOMIC_RELAXED, __HIP_MEMORY_SCOPE_AGENT);
  return __uint_as_float(u);
}
__device__ __forceinline__ void st4(float* p, float v) {
  __hip_atomic_store((unsigned int*)p, __float_as_uint(v), __ATOMIC_RELAXED, __HIP_MEMORY_SCOPE_AGENT);
}
__device__ __forceinline__ void st8(float* p, float a, float b2) {
  unsigned long long v = ((unsigned long long)__float_as_uint(b2) << 32) | (unsigned long long)__float_as_uint(a);
  __hip_atomic_store((unsigned long long*)p, v, __ATOMIC_RELAXED, __HIP_MEMORY_SCOPE_AGENT);
}
__device__ __forceinline__ void atomF(float* p, float v) {
  __hip_atomic_fetch_add(p, v, __ATOMIC_RELAXED, __HIP_MEMORY_SCOPE_AGENT);
}
// 16B coherent load: issue many, then one vmwait()
__device__ __forceinline__ float4 ldg16(const float* p) {
  float4 d;
  asm volatile("global_load_dwordx4 %0, %1, off sc0 sc1" : "=v"(d) : "v"(p));
  return d;
}
__device__ __forceinline__ void vmwait() { asm volatile("s_waitcnt vmcnt(0)" ::: "memory"); }

__device__ __forceinline__ unsigned short tobf(float x) {
  unsigned int u = __float_as_uint(x);
  u += 0x7fffu + ((u >> 16) & 1u);
  return (unsigned short)(u >> 16);
}
__device__ __forceinline__ float frombf(unsigned short s) {
  return __uint_as_float(((unsigned int)s) << 16);
}

// ---------------- setup kernels ----------------

__global__ void k_order(Ctx c) {
  __shared__ int lens[B];
  int tid = threadIdx.x;
  lens[tid] = c.lens_in[tid];
  __syncthreads();
  int li = lens[tid];
  int pos = 0;
  for (int j = 0; j < B; ++j) {
    int lj = lens[j];
    pos += (lj > li || (lj == li && j < tid)) ? 1 : 0;
  }
  c.order_i[pos] = tid;
  c.declen[pos] = li - 1;
  c.out[OUT_ORDR + pos] = (float)tid;
  c.out[OUT_DECL + pos] = (float)(li - 1);
}

__global__ __launch_bounds__(256) void k_caps(Ctx c) {
  int idx = blockIdx.x * 256 + threadIdx.x;
  if (idx < B * MAXLEN) {
    int b = idx / MAXLEN, t = idx - b * MAXLEN;
    int v = c.caps_in[c.order_i[b] * MAXLEN + t];
    c.caps_s[idx] = v;
    c.out[OUT_CAPS + idx] = (float)v;
  }
}

__global__ __launch_bounds__(256) void k_eat(Ctx c) {
  int idx = blockIdx.x * 256 + threadIdx.x;
  if (idx < 128 * 512) {
    int k = idx >> 7, d = idx & 127;
    c.EaT[(size_t)k * 128 + d] = c.eaw[(size_t)d * 512 + k];
  }
}

__global__ __launch_bounds__(256) void k_att1(Ctx c) {
  __shared__ float Xs[8 * 512];
  int tid = threadIdx.x;
  int r0 = blockIdx.x * 8;
  for (int idx = tid; idx < 8 * 512; idx += 256) {
    int rr = idx >> 9, k = idx & 511;
    int r = r0 + rr;
    int b = r / P, p = r - b * P;
    int ob = c.order_i[b];
    Xs[idx] = c.enc[((size_t)(ob * P + p)) * ENCD + k];
  }
  __syncthreads();
  int d = tid >> 1, kh = tid & 1;
  float acc[8];
#pragma unroll
  for (int rr = 0; rr < 8; ++rr) acc[rr] = 0.f;
  int kbase = kh * 256;
  for (int k = 0; k < 256; ++k) {
    float w = c.EaT[(size_t)(kbase + k) * 128 + d];
#pragma unroll
    for (int rr = 0; rr < 8; ++rr) acc[rr] = fmaf(w, Xs[rr * 512 + kbase + k], acc[rr]);
  }
#pragma unroll
  for (int rr = 0; rr < 8; ++rr) {
    acc[rr] += __shfl_xor(acc[rr], 1);
    if (kh == 0) c.att1[(size_t)(r0 + rr) * 128 + d] = acc[rr];
  }
}

// WP1[cg][c][k]: c<192 whh1 row cg*192+c; c<384 whh2; c<416 att (daw|gw1); c<544 fg (ln2g-folded fw1)
__global__ __launch_bounds__(256) void k_wp1(Ctx c) {
  int cg = blockIdx.x;
  float* dst = c.WP1 + (size_t)cg * (P1C * 512);
  for (int idx = threadIdx.x; idx < P1C * 512; idx += 256) {
    int cc = idx >> 9, k = idx & 511;
    float v;
    if (cc < 192) v = c.whh1[(size_t)(cg * 192 + cc) * 512 + k];
    else if (cc < 384) v = c.whh2[(size_t)(cg * 192 + (cc - 192)) * 512 + k];
    else if (cc < 416) {
      int a2 = cg * 32 + (cc - 384);
      v = (a2 < 128) ? c.daw[(size_t)a2 * 512 + k] : c.gw1[(size_t)(a2 - 128) * 512 + k];
    } else {
      int col = cg * 128 + (cc - 416);
      v = c.ln2g[k] * c.fw1[(size_t)col * 512 + k];
    }
    dst[idx] = v;
  }
}

__global__ __launch_bounds__(256) void k_wp2(Ctx c) {
  int cg = blockIdx.x;
  float* dst = c.WP2 + (size_t)cg * (P2C * 1024);
  for (int idx = threadIdx.x; idx < P2C * 1024; idx += 256) {
    int cc = idx >> 10, k = idx & 1023;
    dst[idx] = c.fw2[(size_t)(cg * P2C + cc) * 1024 + k];
  }
}

__global__ __launch_bounds__(256) void k_wp3(Ctx c) {
  int cg = blockIdx.x;
  float* dst = c.WP3 + (size_t)cg * (P3C * 768);
  for (int idx = threadIdx.x; idx < P3C * 768; idx += 256) {
    int cc = idx / 768, k = idx - cc * 768;
    int u = cg * P3C + cc;
    int d = u >> 2, comp = u & 3;
    dst[idx] = (comp < 3) ? c.wih1[(size_t)(comp * 512 + d) * 768 + k]
                          : c.projw[(size_t)d * 768 + k];
  }
}

__global__ __launch_bounds__(256) void k_wp4(Ctx c) {
  int cg = blockIdx.x;
  float* dst = c.WP4 + (size_t)cg * (P4C * 512);
  for (int idx = threadIdx.x; idx < P4C * 512; idx += 256) {
    int cc = idx >> 9, k = idx & 511;
    int u = cg * P4C + cc;
    int d = u / 3, comp = u - d * 3;
    dst[idx] = c.ln1g[k] * c.wih2[(size_t)(comp * 512 + d) * 512 + k];
  }
}

__global__ __launch_bounds__(256) void k_consts(Ctx c) {
  __shared__ float r1[256], r2[256];
  int i = blockIdx.x, tid = threadIdx.x;
  float a = 0.f, b2 = 0.f;
  if (i < 1024) {
    const float* w = c.fw1 + (size_t)i * 512;
    for (int k = tid; k < 512; k += 256) { a = fmaf(c.ln2g[k], w[k], a); b2 = fmaf(c.ln2b[k], w[k], b2); }
  } else {
    const float* w = c.wih2 + (size_t)(i - 1024) * 512;
    for (int k = tid; k < 512; k += 256) { a = fmaf(c.ln1g[k], w[k], a); b2 = fmaf(c.ln1b[k], w[k], b2); }
  }
  r1[tid] = a; r2[tid] = b2;
  __syncthreads();
  for (int s = 128; s > 0; s >>= 1) {
    if (tid < s) { r1[tid] += r1[tid + s]; r2[tid] += r2[tid + s]; }
    __syncthreads();
  }
  if (tid == 0) {
    if (i < 1024) { c.Sf[i] = r1[0]; c.cbf[i] = r2[0] + c.fb1[i]; }
    else { c.Sg[i - 1024] = r1[0]; c.cbg[i - 1024] = r2[0] + c.bih2[i - 1024]; }
  }
}

// ---------------- persistent kernel ----------------

__device__ __forceinline__ void gridbar(int* leafs, int* root, int ph) {
  __builtin_amdgcn_s_waitcnt(0);   // drain this wave's sc1 stores (acked at MALL)
  __syncthreads();
  if (threadIdx.x == 0) {
    int old = __hip_atomic_fetch_add(&leafs[(blockIdx.x & 7) * 32], 1,
                                     __ATOMIC_RELAXED, __HIP_MEMORY_SCOPE_AGENT);
    if (old == ph * 32 - 1)
      __hip_atomic_fetch_add(root, 1, __ATOMIC_RELAXED, __HIP_MEMORY_SCOPE_AGENT);
    while (__hip_atomic_load(root, __ATOMIC_RELAXED, __HIP_MEMORY_SCOPE_AGENT) < ph * 8)
      __builtin_amdgcn_s_sleep(1);
  }
  __syncthreads();
}

__global__ __launch_bounds__(512) void persist(Ctx c) {
  __shared__ unsigned short att1L[196 * 130];  // bf16, row-padded (+2)
  __shared__ unsigned short encL[196 * 128];   // bf16
  __shared__ float XS[3072];
  __shared__ float RED[4352];
  __shared__ float eL[256];
  __shared__ float alphaL[256];
  __shared__ float redS[256];
  __shared__ float att2sL[128], fawL[128], dabL[128], gb1L[128];
  __shared__ float sstat[8];
  __shared__ int declenI[64];
  __shared__ float gateL, gb2v, fabv;

  const int g = blockIdx.x;
  const int tid = threadIdx.x;
  const int cg = g & 7;          // XCD-local weight slice
  const int rg = g >> 3;         // 32 row-groups of 2 rows
  const int r0 = rg * 2;
  const int bA = g >> 2, q = g & 3;  // attention mapping
  const int cs = tid & 127, ks = tid >> 7;     // P1/P2/P3 tiling
  const int cs4 = tid & 63, ks8 = tid >> 6;    // P4 tiling

  // ---- one-time staging ----
  if (tid < 128) {
    fawL[tid] = c.faw[tid];
    dabL[tid] = c.dab[tid] + c.eab[tid];
    gb1L[tid] = c.gb1[tid];
  }
  if (tid == 0) { gb2v = c.gb2[0]; fabv = c.fab[0]; }
  if (tid < 64) declenI[tid] = c.declen[tid];
  {
    const int ob = c.order_i[bA];
    for (int idx = tid; idx < 196 * 128; idx += 512) {
      int p = idx >> 7, j = idx & 127;
      att1L[p * 130 + j] = tobf(c.att1[((size_t)bA * P + p) * 128 + j]);
      encL[idx] = tobf(c.enc[((size_t)(ob * P + p)) * 512 + q * 128 + j]);
    }
  }
  __syncthreads();

  int ph = 0;
  for (int t = 0; t < MAXLEN; ++t) {
    // ===== PHASE1: gh1 | gh2 | att2/gate1 | fg(LN2-folded, relu) ===============
    {
      // stage h1,h2 (XS[0..2048)), v2 (XS[2048..3072)); rows r0..r0+1 contiguous
      const float* p0 = (tid < 256) ? (c.h1 + (size_t)r0 * 512 + tid * 4)
                                    : (c.h2 + (size_t)r0 * 512 + (tid - 256) * 4);
      float4 sA = ldg16(p0);
      float4 sB;
      if (tid < 256) sB = ldg16(c.v2 + (size_t)r0 * 512 + tid * 4);
      if (tid < 2) {
        int slot = (t + 1) & 1;
        float s0 = ld4(c.stats2 + slot * 128 + (r0 + tid) * 2);
        float s1 = ld4(c.stats2 + slot * 128 + (r0 + tid) * 2 + 1);
        float m = s0 * (1.f / 512.f);
        float va = s1 * (1.f / 512.f) - m * m;
        sstat[tid] = m; sstat[2 + tid] = rsqrtf(va + EPS);
      }
      vmwait();
      *(float4*)(XS + tid * 4) = sA;
      if (tid < 256) *(float4*)(XS + 2048 + tid * 4) = sB;
      __syncthreads();

      const int k0 = ks * 128;
      const float* wbase = c.WP1 + (size_t)cg * (P1C * 512);
      const int ncol = (cs < 32) ? 5 : 4;
      for (int ci = 0; ci < ncol; ++ci) {
        const int cc = cs + (ci << 7);
        const float* xb = XS + ((cc < 192) ? 0 : (cc < 416) ? 1024 : 2048) + k0;
        const float* wp = wbase + (size_t)cc * 512 + k0;
        float a0 = 0.f, a1 = 0.f;
#pragma unroll 4
        for (int k = 0; k < 128; k += 4) {
          float4 w = *(const float4*)(wp + k);
          float4 x0 = *(const float4*)(xb + k);
          float4 x1 = *(const float4*)(xb + 512 + k);
          a0 = fmaf(w.x, x0.x, fmaf(w.y, x0.y, fmaf(w.z, x0.z, fmaf(w.w, x0.w, a0))));
          a1 = fmaf(w.x, x1.x, fmaf(w.y, x1.y, fmaf(w.z, x1.z, fmaf(w.w, x1.w, a1))));
        }
        RED[(ks * 2 + 0) * P1C + cc] = a0;
        RED[(ks * 2 + 1) * P1C + cc] = a1;
      }
      __syncthreads();
      for (int pr = tid; pr < 544; pr += 512) {
        int row = pr / 272, cp = (pr % 272) * 2;
        float s0 = 0.f, s1 = 0.f;
#pragma unroll
        for (int kk = 0; kk < 4; ++kk) {
          s0 += RED[(kk * 2 + row) * P1C + cp];
          s1 += RED[(kk * 2 + row) * P1C + cp + 1];
        }
        int bb = r0 + row;
        if (cp < 192) st8(c.gh1g + bb * 1536 + cg * 192 + cp, s0, s1);
        else if (cp < 384) st8(c.gh2g + bb * 1536 + cg * 192 + (cp - 192), s0, s1);
        else if (cp < 416) st8(c.att2acc + bb * 256 + cg * 32 + (cp - 384), s0, s1);
        else {
          int cf = cg * 128 + (cp - 416);
          float m2 = sstat[row], i2 = sstat[2 + row];
          float v0 = i2 * (s0 - m2 * c.Sf[cf]) + c.cbf[cf];
          float v1v = i2 * (s1 - m2 * c.Sf[cf + 1]) + c.cbf[cf + 1];
          st8(c.fgr + bb * 1024 + cf, fmaxf(v0, 0.f), fmaxf(v1v, 0.f));
        }
      }
    }
    gridbar(c.leafs, c.root, ++ph);

    // ===== PHASE2: preds GEMM (store t-1) + stats zero + full attention + gin ===
    {
      float4 sA = ldg16(c.fgr + (size_t)r0 * 1024 + tid * 4);
      if (g == 0) {
        int sl = t & 1;
        if (tid < 128) st4(c.stats1 + sl * 128 + tid, 0.f);
        else if (tid < 256) st4(c.stats2 + sl * 128 + (tid - 128), 0.f);
      }
      vmwait();
      *(float4*)(XS + tid * 4) = sA;
      __syncthreads();

      const int k0 = ks * 256;
      const float* wbase = c.WP2 + (size_t)cg * (P2C * 1024);
      const int c1 = cs + 128;
      const int c1v = (c1 < P2C) ? c1 : (P2C - 1);
      const float* wp0 = wbase + (size_t)cs * 1024 + k0;
      const float* wp1 = wbase + (size_t)c1v * 1024 + k0;
      float a00 = 0.f, a01 = 0.f, a10 = 0.f, a11 = 0.f;
#pragma unroll 4
      for (int k = 0; k < 256; k += 4) {
        float4 x0 = *(const float4*)(XS + k0 + k);
        float4 x1 = *(const float4*)(XS + 1024 + k0 + k);
        float4 w0 = *(const float4*)(wp0 + k);
        float4 w1 = *(const float4*)(wp1 + k);
        a00 = fmaf(w0.x, x0.x, fmaf(w0.y, x0.y, fmaf(w0.z, x0.z, fmaf(w0.w, x0.w, a00))));
        a01 = fmaf(w0.x, x1.x, fmaf(w0.y, x1.y, fmaf(w0.z, x1.z, fmaf(w0.w, x1.w, a01))));
        a10 = fmaf(w1.x, x0.x, fmaf(w1.y, x0.y, fmaf(w1.z, x0.z, fmaf(w1.w, x0.w, a10))));
        a11 = fmaf(w1.x, x1.x, fmaf(w1.y, x1.y, fmaf(w1.z, x1.z, fmaf(w1.w, x1.w, a11))));
      }
      RED[(ks * 2 + 0) * P2C + cs] = a00;
      RED[(ks * 2 + 1) * P2C + cs] = a01;
      if (c1 < P2C) {
        RED[(ks * 2 + 0) * P2C + c1] = a10;
        RED[(ks * 2 + 1) * P2C + c1] = a11;
      }
      __syncthreads();
      if (tid < 500) {
        int row = tid / P2C, cl = tid - row * P2C;
        float s = 0.f;
#pragma unroll
        for (int kk = 0; kk < 4; ++kk) s += RED[(kk * 2 + row) * P2C + cl];
        int bb = r0 + row, vcol = cg * P2C + cl;
        if (t > 0 && (t - 1) < declenI[bb])
          c.out[OUT_PRED + ((size_t)bb * TSTEPS + (t - 1)) * VV + vcol] = s + c.fb2[vcol];
      }
      // ---- attention (per b=bA, redundant across the 4 q-blocks) ----
      if (tid < 128) {
        att2sL[tid] = ld4(c.att2acc + bA * 256 + tid) + dabL[tid];
        float g1 = fmaxf(ld4(c.att2acc + bA * 256 + 128 + tid) + gb1L[tid], 0.f);
        redS[tid] = g1 * c.gw2[tid];
      } else if (tid < 256) redS[tid] = 0.f;
      __syncthreads();
      for (int s2 = 64; s2 > 0; s2 >>= 1) {
        if (tid < s2) redS[tid] += redS[tid + s2];
        __syncthreads();
      }
      if (tid == 0) gateL = sigf(redS[0] + gb2v);
      __syncthreads();
      {
        int p = tid >> 1, jh = tid & 1;
        float e = 0.f;
        if (p < 196) {
          const unsigned short* ap = att1L + p * 130 + jh * 64;
#pragma unroll 8
          for (int j = 0; j < 64; ++j)
            e = fmaf(fmaxf(frombf(ap[j]) + att2sL[jh * 64 + j], 0.f), fawL[jh * 64 + j], e);
        }
        e += __shfl_xor(e, 1);
        if (jh == 0 && p < 196) eL[p] = e + fabv;
      }
      __syncthreads();
      if (tid < 256) redS[tid] = (tid < 196) ? eL[tid] : -3.0e38f;
      __syncthreads();
      for (int s2 = 128; s2 > 0; s2 >>= 1) {
        if (tid < s2) redS[tid] = fmaxf(redS[tid], redS[tid + s2]);
        __syncthreads();
      }
      float mx = redS[0];
      __syncthreads();
      float ex = (tid < 196) ? __expf(eL[tid] - mx) : 0.f;
      if (tid < 256) redS[tid] = ex;
      __syncthreads();
      for (int s2 = 128; s2 > 0; s2 >>= 1) {
        if (tid < s2) redS[tid] += redS[tid + s2];
        __syncthreads();
      }
      float inv = 1.f / redS[0];
      if (tid < 256) alphaL[tid] = ex * inv;
      if (q == 0 && tid < 196 && t < declenI[bA])
        c.out[OUT_ALPH + ((size_t)bA * TSTEPS + t) * P + tid] = ex * inv;
      __syncthreads();
      {
        int el = tid & 127, pq = tid >> 7;
        const unsigned short* ep2 = encL + (size_t)(pq * 49) * 128 + el;
        const float* alp = alphaL + pq * 49;
        float s_ = 0.f;
#pragma unroll
        for (int i = 0; i < 49; ++i) s_ = fmaf(alp[i], frombf(ep2[(size_t)i * 128]), s_);
        RED[tid] = s_;
      }
      __syncthreads();
      if (tid < 128) {
        float aw = RED[tid] + RED[128 + tid] + RED[256 + tid] + RED[384 + tid];
        st4(c.gin + bA * 768 + 256 + q * 128 + tid, aw * gateL);
      }
      if (q == 1 && tid < 256) {
        int tok = c.caps_s[bA * MAXLEN + t];
        st4(c.gin + bA * 768 + tid, c.emb[(size_t)tok * 256 + tid]);
      }
    }
    gridbar(c.leafs, c.root, ++ph);

    // ===== PHASE3: giP GEMM + GRU1 + v1 + stats1 ===============================
    {
      float4 sA;
      if (tid < 384) sA = ldg16(c.gin + (size_t)r0 * 768 + tid * 4);
      vmwait();
      if (tid < 384) *(float4*)(XS + tid * 4) = sA;
      __syncthreads();

      const int k0 = ks * 192;
      const float* wbase = c.WP3 + (size_t)cg * (P3C * 768);
      const float* wp0 = wbase + (size_t)cs * 768 + k0;
      const float* wp1 = wbase + (size_t)(cs + 128) * 768 + k0;
      float a00 = 0.f, a01 = 0.f, a10 = 0.f, a11 = 0.f;
#pragma unroll 4
      for (int k = 0; k < 192; k += 4) {
        float4 x0 = *(const float4*)(XS + k0 + k);
        float4 x1 = *(const float4*)(XS + 768 + k0 + k);
        float4 w0 = *(const float4*)(wp0 + k);
        float4 w1 = *(const float4*)(wp1 + k);
        a00 = fmaf(w0.x, x0.x, fmaf(w0.y, x0.y, fmaf(w0.z, x0.z, fmaf(w0.w, x0.w, a00))));
        a01 = fmaf(w0.x, x1.x, fmaf(w0.y, x1.y, fmaf(w0.z, x1.z, fmaf(w0.w, x1.w, a01))));
        a10 = fmaf(w1.x, x0.x, fmaf(w1.y, x0.y, fmaf(w1.z, x0.z, fmaf(w1.w, x0.w, a10))));
        a11 = fmaf(w1.x, x1.x, fmaf(w1.y, x1.y, fmaf(w1.z, x1.z, fmaf(w1.w, x1.w, a11))));
      }
      RED[(ks * 2 + 0) * P3C + cs] = a00;
      RED[(ks * 2 + 1) * P3C + cs] = a01;
      RED[(ks * 2 + 0) * P3C + cs + 128] = a10;
      RED[(ks * 2 + 1) * P3C + cs + 128] = a11;
      __syncthreads();
      if (tid < 128) {
        int row = tid >> 6, dl = tid & 63;
        int bb = r0 + row, d = (cg << 6) + dl;
        float gi0 = 0.f, gi1 = 0.f, gi2v = 0.f, gi3 = 0.f;
#pragma unroll
        for (int kk = 0; kk < 4; ++kk) {
          const float* rp = RED + (kk * 2 + row) * P3C + dl * 4;
          gi0 += rp[0]; gi1 += rp[1]; gi2v += rp[2]; gi3 += rp[3];
        }
        float gir = gi0 + c.bih1[d];
        float giz = gi1 + c.bih1[512 + d];
        float gig = gi2v + c.bih1[1024 + d];
        float pj = gi3 + c.projb[d];
        float hr = ld4(c.gh1g + bb * 1536 + d) + c.bhh1[d];
        float hz = ld4(c.gh1g + bb * 1536 + 512 + d) + c.bhh1[512 + d];
        float hg = ld4(c.gh1g + bb * 1536 + 1024 + d) + c.bhh1[1024 + d];
        float r_ = sigf(gir + hr);
        float z_ = sigf(giz + hz);
        float n_ = tanhf(gig + r_ * hg);
        float hold = ld4(c.h1 + bb * 512 + d);
        float hnew = (1.f - z_) * n_ + z_ * hold;
        st4(c.h1 + bb * 512 + d, (t < declenI[bb]) ? hnew : hold);
        float v1v = hnew + pj;
        st4(c.v1 + bb * 512 + d, v1v);
        float ss = v1v, sq = v1v * v1v;
#pragma unroll
        for (int w = 1; w < 64; w <<= 1) { ss += __shfl_xor(ss, w); sq += __shfl_xor(sq, w); }
        if (dl == 0) {
          atomF(c.stats1 + (t & 1) * 128 + bb * 2, ss);
          atomF(c.stats1 + (t & 1) * 128 + bb * 2 + 1, sq);
        }
      }
    }
    gridbar(c.leafs, c.root, ++ph);

    // ===== PHASE4: gi2 GEMM (LN1-folded) + GRU2 + v2 + stats2 ==================
    {
      float4 sA;
      if (tid < 256) sA = ldg16(c.v1 + (size_t)r0 * 512 + tid * 4);
      if (tid < 2) {
        float s0 = ld4(c.stats1 + (t & 1) * 128 + (r0 + tid) * 2);
        float s1 = ld4(c.stats1 + (t & 1) * 128 + (r0 + tid) * 2 + 1);
        float m = s0 * (1.f / 512.f);
        float va = s1 * (1.f / 512.f) - m * m;
        sstat[4 + tid] = m; sstat[6 + tid] = rsqrtf(va + EPS);
      }
      vmwait();
      if (tid < 256) *(float4*)(XS + tid * 4) = sA;
      __syncthreads();

      const int k0 = ks8 * 64;
      const float* wbase = c.WP4 + (size_t)cg * (P4C * 512);
      float acc3[3][2];
#pragma unroll
      for (int i = 0; i < 3; ++i) { acc3[i][0] = 0.f; acc3[i][1] = 0.f; }
#pragma unroll
      for (int ci = 0; ci < 3; ++ci) {
        const int cc = cs4 + (ci << 6);
        const float* wp = wbase + (size_t)cc * 512 + k0;
        float a0 = 0.f, a1 = 0.f;
#pragma unroll 4
        for (int k = 0; k < 64; k += 4) {
          float4 w = *(const float4*)(wp + k);
          float4 x0 = *(const float4*)(XS + k0 + k);
          float4 x1 = *(const float4*)(XS + 512 + k0 + k);
          a0 = fmaf(w.x, x0.x, fmaf(w.y, x0.y, fmaf(w.z, x0.z, fmaf(w.w, x0.w, a0))));
          a1 = fmaf(w.x, x1.x, fmaf(w.y, x1.y, fmaf(w.z, x1.z, fmaf(w.w, x1.w, a1))));
        }
        acc3[ci][0] = a0; acc3[ci][1] = a1;
      }
#pragma unroll
      for (int ci = 0; ci < 3; ++ci) {
        const int cc = cs4 + (ci << 6);
        RED[(ks8 * 2 + 0) * P4C + cc] = acc3[ci][0];
        RED[(ks8 * 2 + 1) * P4C + cc] = acc3[ci][1];
      }
      __syncthreads();
      if (tid < 128) {
        int row = tid >> 6, dl = tid & 63;
        int bb = r0 + row, d = (cg << 6) + dl;
        float gi0 = 0.f, gi1 = 0.f, gi2v = 0.f;
#pragma unroll
        for (int kk = 0; kk < 8; ++kk) {
          const float* rp = RED + (kk * 2 + row) * P4C + dl * 3;
          gi0 += rp[0]; gi1 += rp[1]; gi2v += rp[2];
        }
        float m1 = sstat[4 + row], i1 = sstat[6 + row];
        float gir = i1 * (gi0 - m1 * c.Sg[d]) + c.cbg[d];
        float giz = i1 * (gi1 - m1 * c.Sg[512 + d]) + c.cbg[512 + d];
        float gig = i1 * (gi2v - m1 * c.Sg[1024 + d]) + c.cbg[1024 + d];
        float hr = ld4(c.gh2g + bb * 1536 + d) + c.bhh2[d];
        float hz = ld4(c.gh2g + bb * 1536 + 512 + d) + c.bhh2[512 + d];
        float hg = ld4(c.gh2g + bb * 1536 + 1024 + d) + c.bhh2[1024 + d];
        float r_ = sigf(gir + hr);
        float z_ = sigf(giz + hz);
        float n_ = tanhf(gig + r_ * hg);
        float hold = ld4(c.h2 + bb * 512 + d);
        float hnew = (1.f - z_) * n_ + z_ * hold;
        st4(c.h2 + bb * 512 + d, (t < declenI[bb]) ? hnew : hold);
        float h1r = (XS[row * 512 + d] - m1) * i1 * c.ln1g[d] + c.ln1b[d];
        float v2v = hnew + h1r;
        st4(c.v2 + bb * 512 + d, v2v);
        float ss = v2v, sq = v2v * v2v;
#pragma unroll
        for (int w = 1; w < 64; w <<= 1) { ss += __shfl_xor(ss, w); sq += __shfl_xor(sq, w); }
        if (dl == 0) {
          atomF(c.stats2 + (t & 1) * 128 + bb * 2, ss);
          atomF(c.stats2 + (t & 1) * 128 + bb * 2 + 1, sq);
        }
      }
    }
    gridbar(c.leafs, c.root, ++ph);
  }
}

extern "C" void kernel_launch(void* const* d_in, const int* in_sizes, int n_in,
                              void* d_out, int out_size, void* d_ws, size_t ws_size,
                              hipStream_t stream) {
  (void)in_sizes; (void)n_in; (void)ws_size;
  Ctx c;
  c.enc = (const float*)d_in[0];
  c.caps_in = (const int*)d_in[1];
  c.lens_in = (const int*)d_in[2];
  c.eaw = (const float*)d_in[3];
  c.eab = (const float*)d_in[4];
  c.daw = (const float*)d_in[5];
  c.dab = (const float*)d_in[6];
  c.faw = (const float*)d_in[7];
  c.fab = (const float*)d_in[8];
  c.gw1 = (const float*)d_in[9];
  c.gb1 = (const float*)d_in[10];
  c.gw2 = (const float*)d_in[11];
  c.gb2 = (const float*)d_in[12];
  c.emb = (const float*)d_in[13];
  c.wih1 = (const float*)d_in[14];
  c.whh1 = (const float*)d_in[15];
  c.bih1 = (const float*)d_in[16];
  c.bhh1 = (const float*)d_in[17];
  c.wih2 = (const float*)d_in[18];
  c.whh2 = (const float*)d_in[19];
  c.bih2 = (const float*)d_in[20];
  c.bhh2 = (const float*)d_in[21];
  c.projw = (const float*)d_in[22];
  c.projb = (const float*)d_in[23];
  c.ln1g = (const float*)d_in[24];
  c.ln1b = (const float*)d_in[25];
  c.ln2g = (const float*)d_in[26];
  c.ln2b = (const float*)d_in[27];
  c.fw1 = (const float*)d_in[28];
  c.fb1 = (const float*)d_in[29];
  c.fw2 = (const float*)d_in[30];
  c.fb2 = (const float*)d_in[31];
  c.out = (float*)d_out;

  char* wp_ = (char*)d_ws;
  auto alloc = [&](size_t bytes) -> char* {
    char* p = wp_;
    wp_ += (bytes + 255) & ~(size_t)255;
    return p;
  };
  // zero-region (one memset): barriers | h1 | h2 | stats1 | stats2
  char* zbase = wp_;
  c.leafs = (int*)alloc(256 * 4);
  c.root = (int*)alloc(256);
  c.h1 = (float*)alloc((size_t)B * 512 * 4);
  c.h2 = (float*)alloc((size_t)B * 512 * 4);
  c.stats1 = (float*)alloc(2 * 64 * 2 * 4);
  c.stats2 = (float*)alloc(2 * 64 * 2 * 4);
  size_t zbytes = (size_t)(wp_ - zbase);

  c.order_i = (int*)alloc(B * 4);
  c.declen = (int*)alloc(B * 4);
  c.caps_s = (int*)alloc((size_t)B * MAXLEN * 4);
  c.EaT = (float*)alloc((size_t)512 * 128 * 4);
  c.att1 = (float*)alloc((size_t)B * P * 128 * 4);
  c.v1 = (float*)alloc((size_t)B * 512 * 4);
  c.v2 = (float*)alloc((size_t)B * 512 * 4);
  c.gin = (float*)alloc((size_t)B * 768 * 4);
  c.fgr = (float*)alloc((size_t)B * 1024 * 4);
  c.gh1g = (float*)alloc((size_t)B * 1536 * 4);
  c.gh2g = (float*)alloc((size_t)B * 1536 * 4);
  c.att2acc = (float*)alloc((size_t)B * 256 * 4);
  c.WP1 = (float*)alloc((size_t)8 * P1C * 512 * 4);
  c.WP2 = (float*)alloc((size_t)8 * P2C * 1024 * 4);
  c.WP3 = (float*)alloc((size_t)8 * P3C * 768 * 4);
  c.WP4 = (float*)alloc((size_t)8 * P4C * 512 * 4);
  c.Sf = (float*)alloc(1024 * 4);
  c.cbf = (float*)alloc(1024 * 4);
  c.Sg = (float*)alloc(1536 * 4);
  c.cbg = (float*)alloc(1536 * 4);

  hipMemsetAsync(d_out, 0, (size_t)out_size * 4, stream);
  hipMemsetAsync(zbase, 0, zbytes, stream);

  k_order<<<1, 64, 0, stream>>>(c);
  k_caps<<<(B * MAXLEN + 255) / 256, 256, 0, stream>>>(c);
  k_eat<<<(128 * 512 + 255) / 256, 256, 0, stream>>>(c);
  k_att1<<<(B * P) / 8, 256, 0, stream>>>(c);
  k_wp1<<<8, 256, 0, stream>>>(c);
  k_wp2<<<8, 256, 0, stream>>>(c);
  k_wp3<<<8, 256, 0, stream>>>(c);
  k_wp4<<<8, 256, 0, stream>>>(c);
  k_consts<<<2560, 256, 0, stream>>>(c);

  persist<<<256, 512, 0, stream>>>(c);
}